// Round 5
// baseline (500.209 us; speedup 1.0000x reference)
//
#include <hip/hip_runtime.h>
#include <math.h>

#define NB   8
#define NW   200
#define NK   100
#define KSZ  7
#define NHID 150
#define NFE  400
#define NTE  200
#define NG   450   // 3*HID
#define NCIN 300   // 3*K
#define ALPHAC 0.2f

typedef __attribute__((ext_vector_type(8))) short bf8;
typedef __attribute__((ext_vector_type(4))) float f32x4;

__device__ __forceinline__ float sigmoidf_(float x){
  return 1.0f/(1.0f + __expf(-x));
}
__device__ __forceinline__ float tanhf_(float x){
  float xc = fminf(fmaxf(x, -15.f), 15.f);
  float e = __expf(2.f*xc);
  return (e - 1.f)/(e + 1.f);
}
__device__ __forceinline__ unsigned short f2bf(float f){
  unsigned int u = __float_as_uint(f);
  unsigned int r = u + 0x7FFFu + ((u>>16)&1u);
  return (unsigned short)(r>>16);
}

// ---------------- weight prep: conv transpose, w_ih transpose, w_hh -> MFMA B-fragments ----------------
// Bfrag layout: 32 N-tiles x 5 K-steps x 64 lanes x 4 dwords (8 bf16).
// Lane l, elem e (0..7): k = ks*32 + (l>>4)*8 + e, col = tile*16 + (l&15).
// B[k][c] = w_hh[c*150 + k] (zero-padded k>=150, c>=450).
__global__ void prep_kernel(const float* conv_w, const float* w_ih, const float* w_hh,
                            float* conv_wT, float* w_ihT, unsigned int* Bfrag){
  int idx = blockIdx.x*256 + threadIdx.x;
  const int n1 = NK*NK*KSZ;      // 70000
  const int n2 = NG*NCIN;        // 135000
  const int n3 = 32*5*64*4;      // 40960 dwords
  if (idx < n1){
    int k = idx % NK; int it = idx / NK;       // it = i*KSZ + t
    int i = it / KSZ, t = it % KSZ;
    conv_wT[idx] = conv_w[(k*NK + i)*KSZ + t];
  } else if (idx < n1 + n2){
    int o = idx - n1; int g = o % NG; int c = o / NG;
    w_ihT[o] = w_ih[g*NCIN + c];
  } else if (idx < n1 + n2 + n3){
    int o = idx - n1 - n2;
    int n   = o / 1280;
    int rem = o % 1280;
    int ks  = rem / 256;
    int rem2= rem % 256;
    int l   = rem2 >> 2;
    int d   = rem2 & 3;
    int col = n*16 + (l & 15);
    int k0  = ks*32 + (l >> 4)*8 + d*2;
    unsigned short lo = 0, hi = 0;
    if (col < NG){
      if (k0     < NHID) lo = f2bf(w_hh[col*NHID + k0]);
      if (k0 + 1 < NHID) hi = f2bf(w_hh[col*NHID + k0 + 1]);
    }
    Bfrag[o] = ((unsigned int)hi << 16) | lo;
  }
}

// ---------------- conv1d + bias + relu -> xc (B,W,K) ----------------
__global__ void conv_kernel(const float* x, const float* conv_b, const float* conv_wT, float* xc){
  int idx = blockIdx.x*256 + threadIdx.x;
  if (idx >= NB*NW*NK) return;
  int k = idx % NK; int w = (idx/NK) % NW; int b = idx/(NK*NW);
  float acc = conv_b[k];
  const float* xb = x + b*NW*NK;
  for (int t = 0; t < KSZ; ++t){
    int ws = w + t - 3;
    if (ws < 0 || ws >= NW) continue;
    const float* xr = xb + ws*NK;
    const float* wr = conv_wT + t*NK + k;   // (i*KSZ+t)*NK + k
    #pragma unroll 4
    for (int i = 0; i < NK; ++i){
      acc += xr[i] * wr[i*KSZ*NK];
    }
  }
  xc[idx] = fmaxf(acc, 0.0f);
}

// ---------------- f-GAT si/sj: (B,K,FE), nodes=features, v[b,n,d]=xc[b,d,n] ----------------
__global__ void fgat_sisj(const float* xc, const float* f_lin_w, float* si, float* sj){
  __shared__ __align__(16) float vt[NW*4];
  int b = blockIdx.x / 25; int n0 = (blockIdx.x % 25)*4;
  int tid = threadIdx.x;
  for (int idx = tid; idx < NW*4; idx += 512){
    int d = idx >> 2, nn = idx & 3;
    vt[idx] = xc[(b*NW + d)*NK + n0 + nn];
  }
  __syncthreads();
  if (tid >= NFE) return;
  int e = tid;
  float a1[4] = {0,0,0,0}, a2[4] = {0,0,0,0};
  for (int d = 0; d < NW; ++d){
    float w1 = f_lin_w[d*NFE + e];
    float w2 = f_lin_w[(NW + d)*NFE + e];
    float4 v = *(const float4*)&vt[d*4];
    a1[0] += v.x*w1; a1[1] += v.y*w1; a1[2] += v.z*w1; a1[3] += v.w*w1;
    a2[0] += v.x*w2; a2[1] += v.y*w2; a2[2] += v.z*w2; a2[3] += v.w*w2;
  }
  #pragma unroll
  for (int nn = 0; nn < 4; ++nn){
    si[(b*NK + n0+nn)*NFE + e] = a1[nn];
    sj[(b*NK + n0+nn)*NFE + e] = a2[nn];
  }
}

// ---------------- t-GAT si/sj: (B,W,TE), nodes=time, v[b,n,d]=xc[b,n,d] ----------------
__global__ void tgat_sisj(const float* xc, const float* t_lin_w, float* si, float* sj){
  __shared__ __align__(16) float vt[NK*4];
  int b = blockIdx.x / 50; int n0 = (blockIdx.x % 50)*4;
  int tid = threadIdx.x;
  for (int idx = tid; idx < NK*4; idx += 256){
    int d = idx >> 2, nn = idx & 3;
    vt[idx] = xc[(b*NW + n0+nn)*NK + d];
  }
  __syncthreads();
  if (tid >= NTE) return;
  int e = tid;
  float a1[4] = {0,0,0,0}, a2[4] = {0,0,0,0};
  for (int d = 0; d < NK; ++d){
    float w1 = t_lin_w[d*NTE + e];
    float w2 = t_lin_w[(NK + d)*NTE + e];
    float4 v = *(const float4*)&vt[d*4];
    a1[0] += v.x*w1; a1[1] += v.y*w1; a1[2] += v.z*w1; a1[3] += v.w*w1;
    a2[0] += v.x*w2; a2[1] += v.y*w2; a2[2] += v.z*w2; a2[3] += v.w*w2;
  }
  #pragma unroll
  for (int nn = 0; nn < 4; ++nn){
    si[(b*NW + n0+nn)*NTE + e] = a1[nn];
    sj[(b*NW + n0+nn)*NTE + e] = a2[nn];
  }
}

// ---------------- f-GAT attention fused: e -> softmax -> sigmoid(attn@v) ----------------
// out written transposed into (B,W,K): h_featT[b,d,i]
__global__ void fgat_attn(const float* xc, const float* si, const float* sj,
                          const float* f_lin_b, const float* f_a, const float* f_bias,
                          float* h_featT){
  __shared__ float sib[NFE], av[NFE], attn[NK], red[128];
  int b = blockIdx.x / NK, i = blockIdx.x % NK;
  int tid = threadIdx.x;
  for (int e = tid; e < NFE; e += 128){
    sib[e] = si[(b*NK + i)*NFE + e] + f_lin_b[e];
    av[e]  = f_a[e];
  }
  __syncthreads();
  float ej = -1e30f;
  if (tid < NK){
    const float* sjr = sj + (b*NK + tid)*NFE;
    float acc = 0.f;
    for (int e = 0; e < NFE; ++e){
      float tv = sib[e] + sjr[e];
      float lk = fmaxf(tv, 0.f) + ALPHAC*fminf(tv, 0.f);
      acc += av[e]*lk;
    }
    ej = acc + f_bias[i*NK + tid];
  }
  red[tid] = ej; __syncthreads();
  for (int s = 64; s > 0; s >>= 1){ if (tid < s) red[tid] = fmaxf(red[tid], red[tid+s]); __syncthreads(); }
  float m = red[0]; __syncthreads();
  float ex = (tid < NK) ? __expf(ej - m) : 0.f;
  red[tid] = ex; __syncthreads();
  for (int s = 64; s > 0; s >>= 1){ if (tid < s) red[tid] += red[tid+s]; __syncthreads(); }
  float denom = red[0];
  if (tid < NK) attn[tid] = ex / denom;
  __syncthreads();
  for (int d = tid; d < NW; d += 128){
    const float* xr = xc + (b*NW + d)*NK;    // v[b,j,d] = xc[b,d,j]
    float acc = 0.f;
    for (int j = 0; j < NK; ++j) acc += attn[j]*xr[j];
    h_featT[(b*NW + d)*NK + i] = sigmoidf_(acc);
  }
}

// ---------------- t-GAT attention fused -> h_temp (B,W,K) ----------------
__global__ void tgat_attn(const float* xc, const float* si, const float* sj,
                          const float* t_lin_b, const float* t_a, const float* t_bias,
                          float* h_temp){
  __shared__ float sib[NTE], av[NTE], attn[NW], red[256];
  int b = blockIdx.x / NW, i = blockIdx.x % NW;
  int tid = threadIdx.x;
  for (int e = tid; e < NTE; e += 256){
    sib[e] = si[(b*NW + i)*NTE + e] + t_lin_b[e];
    av[e]  = t_a[e];
  }
  __syncthreads();
  float ej = -1e30f;
  if (tid < NW){
    const float* sjr = sj + (b*NW + tid)*NTE;
    float acc = 0.f;
    for (int e = 0; e < NTE; ++e){
      float tv = sib[e] + sjr[e];
      float lk = fmaxf(tv, 0.f) + ALPHAC*fminf(tv, 0.f);
      acc += av[e]*lk;
    }
    ej = acc + t_bias[i*NW + tid];
  }
  red[tid] = ej; __syncthreads();
  for (int s = 128; s > 0; s >>= 1){ if (tid < s) red[tid] = fmaxf(red[tid], red[tid+s]); __syncthreads(); }
  float m = red[0]; __syncthreads();
  float ex = (tid < NW) ? __expf(ej - m) : 0.f;
  red[tid] = ex; __syncthreads();
  for (int s = 128; s > 0; s >>= 1){ if (tid < s) red[tid] += red[tid+s]; __syncthreads(); }
  float denom = red[0];
  if (tid < NW) attn[tid] = ex / denom;
  __syncthreads();
  for (int d = tid; d < NK; d += 256){
    float acc = 0.f;
    for (int j = 0; j < NW; ++j) acc += attn[j]*xc[(b*NW + j)*NK + d];
    h_temp[(b*NW + i)*NK + d] = sigmoidf_(acc);
  }
}

// ---------------- gi = h_cat @ w_ih^T + b_ih, layout (t, b, g) ----------------
__global__ void gi_kernel(const float* xc, const float* h_featT, const float* h_temp,
                          const float* w_ihT, const float* b_ih, float* gi){
  __shared__ __align__(16) float hc[NCIN*8];   // [c][tt], stride 8
  int b = blockIdx.x / 25; int t0 = (blockIdx.x % 25)*8;
  int tid = threadIdx.x;
  for (int idx = tid; idx < NCIN*8; idx += 512){
    int tt = idx / NCIN; int c = idx % NCIN;
    int base = (b*NW + t0 + tt)*NK;
    float v;
    if (c < NK)        v = xc[base + c];
    else if (c < 2*NK) v = h_featT[base + c - NK];
    else               v = h_temp[base + c - 2*NK];
    hc[c*8 + tt] = v;
  }
  __syncthreads();
  if (tid >= NG) return;
  int g = tid;
  float bi = b_ih[g];
  float acc[8];
  #pragma unroll
  for (int tt = 0; tt < 8; ++tt) acc[tt] = bi;
  for (int c = 0; c < NCIN; ++c){
    float wv = w_ihT[c*NG + g];
    float4 h0 = *(const float4*)&hc[c*8];
    float4 h1 = *(const float4*)&hc[c*8+4];
    acc[0] += h0.x*wv; acc[1] += h0.y*wv; acc[2] += h0.z*wv; acc[3] += h0.w*wv;
    acc[4] += h1.x*wv; acc[5] += h1.y*wv; acc[6] += h1.z*wv; acc[7] += h1.w*wv;
  }
  #pragma unroll
  for (int tt = 0; tt < 8; ++tt)
    gi[((t0+tt)*NB + b)*NG + g] = acc[tt];
}

// ---------------- sequential GRU: one block, all 8 batches, MFMA ----------------
// Round-4 failure: compiler REMATERIALIZED the 20 loop-invariant B-fragment
// loads inside the t-loop (VGPR_Count=92 < the 136 needed to hold them) ->
// 164KB/step L2 re-stream. Fix: keep-alive asm ("+v") on every fragment at
// the top of the loop makes reload illegal -> they must stay in VGPRs.
// MFMAs interleaved as 4 independent chains (c0..c3) to hide MFMA latency.
#define MM(C, A, Bf) C = __builtin_amdgcn_mfma_f32_16x16x32_bf16(A, Bf, C, 0, 0, 0);
#define STEP4(A, B0,B1,B2,B3) MM(c0,A,B0) MM(c1,A,B1) MM(c2,A,B2) MM(c3,A,B3)
#define LDB(NM, TL, KS) bf8 NM = Bfrag[((TL)*5 + (KS))*64 + lane];

__global__ void __launch_bounds__(512, 2) gru_kernel(const float* gi, const bf8* Bfrag,
                                                     const float* b_hh, float* out){
  __shared__ __align__(16) unsigned short h_hi[16*176];
  __shared__ __align__(16) unsigned short h_lo[16*176];
  __shared__ __align__(16) float h_f32[8*152];
  __shared__ __align__(16) float gh[16*516];
  int tid = threadIdx.x;
  int lane = tid & 63;
  int wv = tid >> 6;            // wave 0..7
  int agrp = lane >> 4;         // 0..3
  int arow = lane & 15;
  int crow = agrp*4;
  int ccol = arow;

  // gate-phase pair assignments (fixed per thread)
  int p0 = tid, p1 = tid + 512, p2 = tid + 1024;
  int b0 = p0/NHID, u0 = p0%NHID;
  int b1 = p1/NHID, u1 = p1%NHID;
  bool v2 = (p2 < NB*NHID);
  int b2 = v2 ? p2/NHID : 0, u2 = v2 ? p2%NHID : 0;
  float bhr0 = b_hh[u0],      bhz0 = b_hh[NHID+u0],  bhn0 = b_hh[2*NHID+u0];
  float bhr1 = b_hh[u1],      bhz1 = b_hh[NHID+u1],  bhn1 = b_hh[2*NHID+u1];
  float bhr2 = b_hh[u2],      bhz2 = b_hh[NHID+u2],  bhn2 = b_hh[2*NHID+u2];

  // B-fragments: tiles wv, wv+8, wv+16, wv+24 (named, loop-invariant)
  LDB(W00,wv,0)    LDB(W01,wv,1)    LDB(W02,wv,2)    LDB(W03,wv,3)    LDB(W04,wv,4)
  LDB(W10,wv+8,0)  LDB(W11,wv+8,1)  LDB(W12,wv+8,2)  LDB(W13,wv+8,3)  LDB(W14,wv+8,4)
  LDB(W20,wv+16,0) LDB(W21,wv+16,1) LDB(W22,wv+16,2) LDB(W23,wv+16,3) LDB(W24,wv+16,4)
  LDB(W30,wv+24,0) LDB(W31,wv+24,1) LDB(W32,wv+24,2) LDB(W33,wv+24,3) LDB(W34,wv+24,4)

  for (int i = tid; i < 16*176; i += 512){ h_hi[i] = 0; h_lo[i] = 0; }
  for (int i = tid; i < 8*152;  i += 512){ h_f32[i] = 0.f; }
  __syncthreads();

  const bf8* HH = (const bf8*)h_hi;
  const bf8* HL = (const bf8*)h_lo;
  int abase = arow*22 + agrp;   // bf8 units; row stride 176 bf16 = 22 bf8

  for (int t = 0; t < NW; ++t){
    // keep-alive: forbids rematerializing the W loads inside the loop
    asm volatile("" : "+v"(W00),"+v"(W01),"+v"(W02),"+v"(W03),"+v"(W04),
                      "+v"(W10),"+v"(W11),"+v"(W12),"+v"(W13),"+v"(W14));
    asm volatile("" : "+v"(W20),"+v"(W21),"+v"(W22),"+v"(W23),"+v"(W24),
                      "+v"(W30),"+v"(W31),"+v"(W32),"+v"(W33),"+v"(W34));

    // prefetch this step's gi (consumed after barrier 1)
    const float* gt = gi + t*NB*NG;
    float gr0 = gt[b0*NG+u0], gz0 = gt[b0*NG+NHID+u0], gn0 = gt[b0*NG+2*NHID+u0];
    float gr1 = gt[b1*NG+u1], gz1 = gt[b1*NG+NHID+u1], gn1 = gt[b1*NG+2*NHID+u1];
    float gr2 = 0.f, gz2 = 0.f, gn2 = 0.f;
    if (v2){ gr2 = gt[b2*NG+u2]; gz2 = gt[b2*NG+NHID+u2]; gn2 = gt[b2*NG+2*NHID+u2]; }

    // A fragments (hi/lo), shared across this wave's 4 tiles
    bf8 aH0 = HH[abase],    aH1 = HH[abase+4],  aH2 = HH[abase+8],
        aH3 = HH[abase+12], aH4 = HH[abase+16];
    bf8 aL0 = HL[abase],    aL1 = HL[abase+4],  aL2 = HL[abase+8],
        aL3 = HL[abase+12], aL4 = HL[abase+16];

    f32x4 c0 = {0.f,0.f,0.f,0.f}, c1 = {0.f,0.f,0.f,0.f},
          c2 = {0.f,0.f,0.f,0.f}, c3 = {0.f,0.f,0.f,0.f};
    STEP4(aH0, W00,W10,W20,W30)
    STEP4(aL0, W00,W10,W20,W30)
    STEP4(aH1, W01,W11,W21,W31)
    STEP4(aL1, W01,W11,W21,W31)
    STEP4(aH2, W02,W12,W22,W32)
    STEP4(aL2, W02,W12,W22,W32)
    STEP4(aH3, W03,W13,W23,W33)
    STEP4(aL3, W03,W13,W23,W33)
    STEP4(aH4, W04,W14,W24,W34)
    STEP4(aL4, W04,W14,W24,W34)

    if (agrp < 2){   // rows 0..7 are real batches
      float* g0 = &gh[crow*516 + (wv   )*16 + ccol];
      float* g1 = &gh[crow*516 + (wv+ 8)*16 + ccol];
      float* g2 = &gh[crow*516 + (wv+16)*16 + ccol];
      float* g3 = &gh[crow*516 + (wv+24)*16 + ccol];
      g0[0]=c0[0]; g0[516]=c0[1]; g0[1032]=c0[2]; g0[1548]=c0[3];
      g1[0]=c1[0]; g1[516]=c1[1]; g1[1032]=c1[2]; g1[1548]=c1[3];
      g2[0]=c2[0]; g2[516]=c2[1]; g2[1032]=c2[2]; g2[1548]=c2[3];
      g3[0]=c3[0]; g3[516]=c3[1]; g3[1032]=c3[2]; g3[1548]=c3[3];
    }
    __syncthreads();

    // gate phase
    {
      float r = sigmoidf_(gr0 + gh[b0*516+u0] + bhr0);
      float z = sigmoidf_(gz0 + gh[b0*516+NHID+u0] + bhz0);
      float n = tanhf_  (gn0 + r*(gh[b0*516+2*NHID+u0] + bhn0));
      float hold = h_f32[b0*152+u0];
      float hn = (1.f - z)*n + z*hold;
      h_f32[b0*152+u0] = hn;
      unsigned int ub = __float_as_uint(hn);
      unsigned int hi = (ub + 0x7FFFu + ((ub>>16)&1u)) >> 16;
      h_hi[b0*176+u0] = (unsigned short)hi;
      float lo = hn - __uint_as_float(hi<<16);
      unsigned int ul = __float_as_uint(lo);
      h_lo[b0*176+u0] = (unsigned short)((ul + 0x7FFFu + ((ul>>16)&1u)) >> 16);
    }
    {
      float r = sigmoidf_(gr1 + gh[b1*516+u1] + bhr1);
      float z = sigmoidf_(gz1 + gh[b1*516+NHID+u1] + bhz1);
      float n = tanhf_  (gn1 + r*(gh[b1*516+2*NHID+u1] + bhn1));
      float hold = h_f32[b1*152+u1];
      float hn = (1.f - z)*n + z*hold;
      h_f32[b1*152+u1] = hn;
      unsigned int ub = __float_as_uint(hn);
      unsigned int hi = (ub + 0x7FFFu + ((ub>>16)&1u)) >> 16;
      h_hi[b1*176+u1] = (unsigned short)hi;
      float lo = hn - __uint_as_float(hi<<16);
      unsigned int ul = __float_as_uint(lo);
      h_lo[b1*176+u1] = (unsigned short)((ul + 0x7FFFu + ((ul>>16)&1u)) >> 16);
    }
    if (v2){
      float r = sigmoidf_(gr2 + gh[b2*516+u2] + bhr2);
      float z = sigmoidf_(gz2 + gh[b2*516+NHID+u2] + bhz2);
      float n = tanhf_  (gn2 + r*(gh[b2*516+2*NHID+u2] + bhn2));
      float hold = h_f32[b2*152+u2];
      float hn = (1.f - z)*n + z*hold;
      h_f32[b2*152+u2] = hn;
      unsigned int ub = __float_as_uint(hn);
      unsigned int hi = (ub + 0x7FFFu + ((ub>>16)&1u)) >> 16;
      h_hi[b2*176+u2] = (unsigned short)hi;
      float lo = hn - __uint_as_float(hi<<16);
      unsigned int ul = __float_as_uint(lo);
      h_lo[b2*176+u2] = (unsigned short)((ul + 0x7FFFu + ((ul>>16)&1u)) >> 16);
    }
    __syncthreads();
  }

  out[b0*NHID + u0] = h_f32[b0*152 + u0];
  out[b1*NHID + u1] = h_f32[b1*152 + u1];
  if (v2) out[b2*NHID + u2] = h_f32[b2*152 + u2];
}

extern "C" void kernel_launch(void* const* d_in, const int* in_sizes, int n_in,
                              void* d_out, int out_size, void* d_ws, size_t ws_size,
                              hipStream_t stream){
  const float* x       = (const float*)d_in[0];
  const float* conv_w  = (const float*)d_in[1];
  const float* conv_b  = (const float*)d_in[2];
  const float* f_lin_w = (const float*)d_in[3];
  const float* f_lin_b = (const float*)d_in[4];
  const float* f_a     = (const float*)d_in[5];
  const float* f_bias  = (const float*)d_in[6];
  const float* t_lin_w = (const float*)d_in[7];
  const float* t_lin_b = (const float*)d_in[8];
  const float* t_a     = (const float*)d_in[9];
  const float* t_bias  = (const float*)d_in[10];
  const float* w_ih    = (const float*)d_in[11];
  const float* w_hh    = (const float*)d_in[12];
  const float* b_ih    = (const float*)d_in[13];
  const float* b_hh    = (const float*)d_in[14];

  float* ws      = (float*)d_ws;
  float* xc      = ws;               // 160000
  float* conv_wT = ws + 160000;      // 70000
  float* si_f    = ws + 230000;      // 320000
  float* sj_f    = ws + 550000;      // 320000
  float* h_featT = ws + 870000;      // 160000
  float* si_t    = ws + 1030000;     // 320000
  float* sj_t    = ws + 1350000;     // 320000
  float* h_temp  = ws + 1670000;     // 160000
  float* w_ihT   = ws + 1830000;     // 135000
  float* gi      = ws + 1965000;     // 720000
  float* BfragF  = ws + 2685000;     // 40960 dwords (16B-aligned offset)
                                     // total 2725960 floats ~= 10.9 MB

  prep_kernel<<<961, 256, 0, stream>>>(conv_w, w_ih, w_hh, conv_wT, w_ihT, (unsigned int*)BfragF);
  conv_kernel<<<(NB*NW*NK + 255)/256, 256, 0, stream>>>(x, conv_b, conv_wT, xc);
  fgat_sisj<<<NB*25, 512, 0, stream>>>(xc, f_lin_w, si_f, sj_f);
  tgat_sisj<<<NB*50, 256, 0, stream>>>(xc, t_lin_w, si_t, sj_t);
  fgat_attn<<<NB*NK, 128, 0, stream>>>(xc, si_f, sj_f, f_lin_b, f_a, f_bias, h_featT);
  tgat_attn<<<NB*NW, 256, 0, stream>>>(xc, si_t, sj_t, t_lin_b, t_a, t_bias, h_temp);
  gi_kernel<<<NB*25, 512, 0, stream>>>(xc, h_featT, h_temp, w_ihT, b_ih, gi);
  gru_kernel<<<1, 512, 0, stream>>>(gi, (const bf8*)BfragF, b_hh, (float*)d_out);
}

// Round 6
// 434.669 us; speedup vs baseline: 1.1508x; 1.1508x over previous
//
#include <hip/hip_runtime.h>
#include <math.h>

#define NB   8
#define NW   200
#define NK   100
#define KSZ  7
#define NHID 150
#define NFE  400
#define NTE  200
#define NG   450   // 3*HID
#define NCIN 300   // 3*K
#define ALPHAC 0.2f

typedef __attribute__((ext_vector_type(8))) short bf8;
typedef __attribute__((ext_vector_type(4))) float f32x4;

__device__ __forceinline__ float sigmoidf_(float x){
  return 1.0f/(1.0f + __expf(-x));
}
__device__ __forceinline__ float tanhf_(float x){
  float xc = fminf(fmaxf(x, -15.f), 15.f);
  float e = __expf(2.f*xc);
  return (e - 1.f)/(e + 1.f);
}
__device__ __forceinline__ unsigned short f2bf(float f){
  unsigned int u = __float_as_uint(f);
  unsigned int r = u + 0x7FFFu + ((u>>16)&1u);
  return (unsigned short)(r>>16);
}

// ---------------- weight prep: conv transpose, w_ih transpose, w_hh -> MFMA B-fragments ----------------
// Bfrag layout: 32 N-tiles x 5 K-steps x 64 lanes x 4 dwords (8 bf16).
// Lane l, dword d: k0 = ks*32 + (l>>4)*8 + d*2 (pair k0,k0+1 packed lo|hi), col = tile*16 + (l&15).
// B[k][c] = w_hh[c*150 + k] (zero-padded k>=150, c>=450).
__global__ void prep_kernel(const float* conv_w, const float* w_ih, const float* w_hh,
                            float* conv_wT, float* w_ihT, unsigned int* Bfrag){
  int idx = blockIdx.x*256 + threadIdx.x;
  const int n1 = NK*NK*KSZ;      // 70000
  const int n2 = NG*NCIN;        // 135000
  const int n3 = 32*5*64*4;      // 40960 dwords
  if (idx < n1){
    int k = idx % NK; int it = idx / NK;       // it = i*KSZ + t
    int i = it / KSZ, t = it % KSZ;
    conv_wT[idx] = conv_w[(k*NK + i)*KSZ + t];
  } else if (idx < n1 + n2){
    int o = idx - n1; int g = o % NG; int c = o / NG;
    w_ihT[o] = w_ih[g*NCIN + c];
  } else if (idx < n1 + n2 + n3){
    int o = idx - n1 - n2;
    int n   = o / 1280;
    int rem = o % 1280;
    int ks  = rem / 256;
    int rem2= rem % 256;
    int l   = rem2 >> 2;
    int d   = rem2 & 3;
    int col = n*16 + (l & 15);
    int k0  = ks*32 + (l >> 4)*8 + d*2;
    unsigned short lo = 0, hi = 0;
    if (col < NG){
      if (k0     < NHID) lo = f2bf(w_hh[col*NHID + k0]);
      if (k0 + 1 < NHID) hi = f2bf(w_hh[col*NHID + k0 + 1]);
    }
    Bfrag[o] = ((unsigned int)hi << 16) | lo;
  }
}

// ---------------- conv1d + bias + relu -> xc (B,W,K) ----------------
__global__ void conv_kernel(const float* x, const float* conv_b, const float* conv_wT, float* xc){
  int idx = blockIdx.x*256 + threadIdx.x;
  if (idx >= NB*NW*NK) return;
  int k = idx % NK; int w = (idx/NK) % NW; int b = idx/(NK*NW);
  float acc = conv_b[k];
  const float* xb = x + b*NW*NK;
  for (int t = 0; t < KSZ; ++t){
    int ws = w + t - 3;
    if (ws < 0 || ws >= NW) continue;
    const float* xr = xb + ws*NK;
    const float* wr = conv_wT + t*NK + k;   // (i*KSZ+t)*NK + k
    #pragma unroll 4
    for (int i = 0; i < NK; ++i){
      acc += xr[i] * wr[i*KSZ*NK];
    }
  }
  xc[idx] = fmaxf(acc, 0.0f);
}

// ---------------- f-GAT si/sj: (B,K,FE), nodes=features, v[b,n,d]=xc[b,d,n] ----------------
__global__ void fgat_sisj(const float* xc, const float* f_lin_w, float* si, float* sj){
  __shared__ __align__(16) float vt[NW*4];
  int b = blockIdx.x / 25; int n0 = (blockIdx.x % 25)*4;
  int tid = threadIdx.x;
  for (int idx = tid; idx < NW*4; idx += 512){
    int d = idx >> 2, nn = idx & 3;
    vt[idx] = xc[(b*NW + d)*NK + n0 + nn];
  }
  __syncthreads();
  if (tid >= NFE) return;
  int e = tid;
  float a1[4] = {0,0,0,0}, a2[4] = {0,0,0,0};
  for (int d = 0; d < NW; ++d){
    float w1 = f_lin_w[d*NFE + e];
    float w2 = f_lin_w[(NW + d)*NFE + e];
    float4 v = *(const float4*)&vt[d*4];
    a1[0] += v.x*w1; a1[1] += v.y*w1; a1[2] += v.z*w1; a1[3] += v.w*w1;
    a2[0] += v.x*w2; a2[1] += v.y*w2; a2[2] += v.z*w2; a2[3] += v.w*w2;
  }
  #pragma unroll
  for (int nn = 0; nn < 4; ++nn){
    si[(b*NK + n0+nn)*NFE + e] = a1[nn];
    sj[(b*NK + n0+nn)*NFE + e] = a2[nn];
  }
}

// ---------------- t-GAT si/sj: (B,W,TE), nodes=time, v[b,n,d]=xc[b,n,d] ----------------
__global__ void tgat_sisj(const float* xc, const float* t_lin_w, float* si, float* sj){
  __shared__ __align__(16) float vt[NK*4];
  int b = blockIdx.x / 50; int n0 = (blockIdx.x % 50)*4;
  int tid = threadIdx.x;
  for (int idx = tid; idx < NK*4; idx += 256){
    int d = idx >> 2, nn = idx & 3;
    vt[idx] = xc[(b*NW + n0+nn)*NK + d];
  }
  __syncthreads();
  if (tid >= NTE) return;
  int e = tid;
  float a1[4] = {0,0,0,0}, a2[4] = {0,0,0,0};
  for (int d = 0; d < NK; ++d){
    float w1 = t_lin_w[d*NTE + e];
    float w2 = t_lin_w[(NK + d)*NTE + e];
    float4 v = *(const float4*)&vt[d*4];
    a1[0] += v.x*w1; a1[1] += v.y*w1; a1[2] += v.z*w1; a1[3] += v.w*w1;
    a2[0] += v.x*w2; a2[1] += v.y*w2; a2[2] += v.z*w2; a2[3] += v.w*w2;
  }
  #pragma unroll
  for (int nn = 0; nn < 4; ++nn){
    si[(b*NW + n0+nn)*NTE + e] = a1[nn];
    sj[(b*NW + n0+nn)*NTE + e] = a2[nn];
  }
}

// ---------------- f-GAT attention fused: e -> softmax -> sigmoid(attn@v) ----------------
// out written transposed into (B,W,K): h_featT[b,d,i]
__global__ void fgat_attn(const float* xc, const float* si, const float* sj,
                          const float* f_lin_b, const float* f_a, const float* f_bias,
                          float* h_featT){
  __shared__ float sib[NFE], av[NFE], attn[NK], red[128];
  int b = blockIdx.x / NK, i = blockIdx.x % NK;
  int tid = threadIdx.x;
  for (int e = tid; e < NFE; e += 128){
    sib[e] = si[(b*NK + i)*NFE + e] + f_lin_b[e];
    av[e]  = f_a[e];
  }
  __syncthreads();
  float ej = -1e30f;
  if (tid < NK){
    const float* sjr = sj + (b*NK + tid)*NFE;
    float acc = 0.f;
    for (int e = 0; e < NFE; ++e){
      float tv = sib[e] + sjr[e];
      float lk = fmaxf(tv, 0.f) + ALPHAC*fminf(tv, 0.f);
      acc += av[e]*lk;
    }
    ej = acc + f_bias[i*NK + tid];
  }
  red[tid] = ej; __syncthreads();
  for (int s = 64; s > 0; s >>= 1){ if (tid < s) red[tid] = fmaxf(red[tid], red[tid+s]); __syncthreads(); }
  float m = red[0]; __syncthreads();
  float ex = (tid < NK) ? __expf(ej - m) : 0.f;
  red[tid] = ex; __syncthreads();
  for (int s = 64; s > 0; s >>= 1){ if (tid < s) red[tid] += red[tid+s]; __syncthreads(); }
  float denom = red[0];
  if (tid < NK) attn[tid] = ex / denom;
  __syncthreads();
  for (int d = tid; d < NW; d += 128){
    const float* xr = xc + (b*NW + d)*NK;    // v[b,j,d] = xc[b,d,j]
    float acc = 0.f;
    for (int j = 0; j < NK; ++j) acc += attn[j]*xr[j];
    h_featT[(b*NW + d)*NK + i] = sigmoidf_(acc);
  }
}

// ---------------- t-GAT attention fused -> h_temp (B,W,K) ----------------
__global__ void tgat_attn(const float* xc, const float* si, const float* sj,
                          const float* t_lin_b, const float* t_a, const float* t_bias,
                          float* h_temp){
  __shared__ float sib[NTE], av[NTE], attn[NW], red[256];
  int b = blockIdx.x / NW, i = blockIdx.x % NW;
  int tid = threadIdx.x;
  for (int e = tid; e < NTE; e += 256){
    sib[e] = si[(b*NW + i)*NTE + e] + t_lin_b[e];
    av[e]  = t_a[e];
  }
  __syncthreads();
  float ej = -1e30f;
  if (tid < NW){
    const float* sjr = sj + (b*NW + tid)*NTE;
    float acc = 0.f;
    for (int e = 0; e < NTE; ++e){
      float tv = sib[e] + sjr[e];
      float lk = fmaxf(tv, 0.f) + ALPHAC*fminf(tv, 0.f);
      acc += av[e]*lk;
    }
    ej = acc + t_bias[i*NW + tid];
  }
  red[tid] = ej; __syncthreads();
  for (int s = 128; s > 0; s >>= 1){ if (tid < s) red[tid] = fmaxf(red[tid], red[tid+s]); __syncthreads(); }
  float m = red[0]; __syncthreads();
  float ex = (tid < NW) ? __expf(ej - m) : 0.f;
  red[tid] = ex; __syncthreads();
  for (int s = 128; s > 0; s >>= 1){ if (tid < s) red[tid] += red[tid+s]; __syncthreads(); }
  float denom = red[0];
  if (tid < NW) attn[tid] = ex / denom;
  __syncthreads();
  for (int d = tid; d < NK; d += 256){
    float acc = 0.f;
    for (int j = 0; j < NW; ++j) acc += attn[j]*xc[(b*NW + j)*NK + d];
    h_temp[(b*NW + i)*NK + d] = sigmoidf_(acc);
  }
}

// ---------------- gi = h_cat @ w_ih^T + b_ih, layout (t, b, g) ----------------
__global__ void gi_kernel(const float* xc, const float* h_featT, const float* h_temp,
                          const float* w_ihT, const float* b_ih, float* gi){
  __shared__ __align__(16) float hc[NCIN*8];   // [c][tt], stride 8
  int b = blockIdx.x / 25; int t0 = (blockIdx.x % 25)*8;
  int tid = threadIdx.x;
  for (int idx = tid; idx < NCIN*8; idx += 512){
    int tt = idx / NCIN; int c = idx % NCIN;
    int base = (b*NW + t0 + tt)*NK;
    float v;
    if (c < NK)        v = xc[base + c];
    else if (c < 2*NK) v = h_featT[base + c - NK];
    else               v = h_temp[base + c - 2*NK];
    hc[c*8 + tt] = v;
  }
  __syncthreads();
  if (tid >= NG) return;
  int g = tid;
  float bi = b_ih[g];
  float acc[8];
  #pragma unroll
  for (int tt = 0; tt < 8; ++tt) acc[tt] = bi;
  for (int c = 0; c < NCIN; ++c){
    float wv = w_ihT[c*NG + g];
    float4 h0 = *(const float4*)&hc[c*8];
    float4 h1 = *(const float4*)&hc[c*8+4];
    acc[0] += h0.x*wv; acc[1] += h0.y*wv; acc[2] += h0.z*wv; acc[3] += h0.w*wv;
    acc[4] += h1.x*wv; acc[5] += h1.y*wv; acc[6] += h1.z*wv; acc[7] += h1.w*wv;
  }
  #pragma unroll
  for (int tt = 0; tt < 8; ++tt)
    gi[((t0+tt)*NB + b)*NG + g] = acc[tt];
}

// ---------------- sequential GRU: one block, all 8 batches, MFMA + AGPR weights ----------------
// Rounds 4-5: the allocator refuses to hold 80 VGPRs of loop-invariant
// B-fragments (remat round 4, scratch-spill round 5). Fix: place them in
// AGPRs a0..a79 by hand (v_accvgpr_write at init; MFMA B operand reads
// AGPR directly on gfx950). Also: hi rows 0-7 / lo rows 8-15 packed in ONE
// A fragment -> 20 MFMAs/wave/step (was 40) and half the A-frag LDS reads;
// gate phase sums C[b] + C[b+8].
#define STASH(B0,B1,B2,B3, FR) { \
  int4 wq = Bq[(FR)*64 + lane]; \
  asm volatile("v_accvgpr_write_b32 " B0 ", %0\n\t" \
               "v_accvgpr_write_b32 " B1 ", %1\n\t" \
               "v_accvgpr_write_b32 " B2 ", %2\n\t" \
               "v_accvgpr_write_b32 " B3 ", %3" \
               :: "v"(wq.x), "v"(wq.y), "v"(wq.z), "v"(wq.w) \
               : B0, B1, B2, B3); }
#define MMA_INIT(ACC, AF, BR, C0,C1,C2,C3) \
  asm volatile("v_mfma_f32_16x16x32_bf16 %0, %1, " BR ", 0" \
               : "=v"(ACC) : "v"(AF) : C0,C1,C2,C3);
#define MMA_ACC(ACC, AF, BR, C0,C1,C2,C3) \
  asm volatile("v_mfma_f32_16x16x32_bf16 %0, %1, " BR ", %0" \
               : "+v"(ACC) : "v"(AF) : C0,C1,C2,C3);

__global__ void __launch_bounds__(512, 2) gru_kernel(const float* gi, const int4* Bq,
                                                     const float* b_hh, float* out){
  __shared__ __align__(16) unsigned short h_bf[16*176];   // rows 0-7 hi, 8-15 lo
  __shared__ __align__(16) float h_f32[8*152];
  __shared__ __align__(16) float gh[16*516];
  int tid = threadIdx.x;
  int lane = tid & 63;
  int wv = tid >> 6;            // wave 0..7
  int agrp = lane >> 4;         // 0..3
  int arow = lane & 15;
  int crow = agrp*4;
  int ccol = arow;

  // gate-phase pair assignments (fixed per thread)
  int p0 = tid, p1 = tid + 512, p2 = tid + 1024;
  int b0 = p0/NHID, u0 = p0%NHID;
  int b1 = p1/NHID, u1 = p1%NHID;
  bool v2 = (p2 < NB*NHID);
  int b2 = v2 ? p2/NHID : 0, u2 = v2 ? p2%NHID : 0;
  float bhr0 = b_hh[u0], bhz0 = b_hh[NHID+u0], bhn0 = b_hh[2*NHID+u0];
  float bhr1 = b_hh[u1], bhz1 = b_hh[NHID+u1], bhn1 = b_hh[2*NHID+u1];
  float bhr2 = b_hh[u2], bhz2 = b_hh[NHID+u2], bhn2 = b_hh[2*NHID+u2];

  // stash the 20 B-fragments (tiles wv, wv+8, wv+16, wv+24; 5 K-steps) in a0..a79
  STASH("a0","a1","a2","a3",     (wv)*5+0)
  STASH("a4","a5","a6","a7",     (wv)*5+1)
  STASH("a8","a9","a10","a11",   (wv)*5+2)
  STASH("a12","a13","a14","a15", (wv)*5+3)
  STASH("a16","a17","a18","a19", (wv)*5+4)
  STASH("a20","a21","a22","a23", (wv+8)*5+0)
  STASH("a24","a25","a26","a27", (wv+8)*5+1)
  STASH("a28","a29","a30","a31", (wv+8)*5+2)
  STASH("a32","a33","a34","a35", (wv+8)*5+3)
  STASH("a36","a37","a38","a39", (wv+8)*5+4)
  STASH("a40","a41","a42","a43", (wv+16)*5+0)
  STASH("a44","a45","a46","a47", (wv+16)*5+1)
  STASH("a48","a49","a50","a51", (wv+16)*5+2)
  STASH("a52","a53","a54","a55", (wv+16)*5+3)
  STASH("a56","a57","a58","a59", (wv+16)*5+4)
  STASH("a60","a61","a62","a63", (wv+24)*5+0)
  STASH("a64","a65","a66","a67", (wv+24)*5+1)
  STASH("a68","a69","a70","a71", (wv+24)*5+2)
  STASH("a72","a73","a74","a75", (wv+24)*5+3)
  STASH("a76","a77","a78","a79", (wv+24)*5+4)

  for (int i = tid; i < 16*176; i += 512) h_bf[i] = 0;
  for (int i = tid; i < 8*152;  i += 512) h_f32[i] = 0.f;
  __syncthreads();

  const bf8* HB = (const bf8*)h_bf;
  int abase = arow*22 + agrp;   // bf8 units; row stride 176 bf16 = 22 bf8

  for (int t = 0; t < NW; ++t){
    // prefetch this step's gi (consumed after the barrier)
    const float* gt = gi + t*NB*NG;
    float gr0 = gt[b0*NG+u0], gz0 = gt[b0*NG+NHID+u0], gn0 = gt[b0*NG+2*NHID+u0];
    float gr1 = gt[b1*NG+u1], gz1 = gt[b1*NG+NHID+u1], gn1 = gt[b1*NG+2*NHID+u1];
    float gr2 = 0.f, gz2 = 0.f, gn2 = 0.f;
    if (v2){ gr2 = gt[b2*NG+u2]; gz2 = gt[b2*NG+NHID+u2]; gn2 = gt[b2*NG+2*NHID+u2]; }

    // A fragments: rows 0-7 hi(batch), 8-15 lo(batch); shared by this wave's 4 tiles
    bf8 A0 = HB[abase],    A1 = HB[abase+4],  A2 = HB[abase+8],
        A3 = HB[abase+12], A4 = HB[abase+16];

    f32x4 c0, c1, c2, c3;
    MMA_INIT(c0, A0, "a[0:3]",   "a0","a1","a2","a3")
    MMA_INIT(c1, A0, "a[20:23]", "a20","a21","a22","a23")
    MMA_INIT(c2, A0, "a[40:43]", "a40","a41","a42","a43")
    MMA_INIT(c3, A0, "a[60:63]", "a60","a61","a62","a63")
    MMA_ACC (c0, A1, "a[4:7]",   "a4","a5","a6","a7")
    MMA_ACC (c1, A1, "a[24:27]", "a24","a25","a26","a27")
    MMA_ACC (c2, A1, "a[44:47]", "a44","a45","a46","a47")
    MMA_ACC (c3, A1, "a[64:67]", "a64","a65","a66","a67")
    MMA_ACC (c0, A2, "a[8:11]",  "a8","a9","a10","a11")
    MMA_ACC (c1, A2, "a[28:31]", "a28","a29","a30","a31")
    MMA_ACC (c2, A2, "a[48:51]", "a48","a49","a50","a51")
    MMA_ACC (c3, A2, "a[68:71]", "a68","a69","a70","a71")
    MMA_ACC (c0, A3, "a[12:15]", "a12","a13","a14","a15")
    MMA_ACC (c1, A3, "a[32:35]", "a32","a33","a34","a35")
    MMA_ACC (c2, A3, "a[52:55]", "a52","a53","a54","a55")
    MMA_ACC (c3, A3, "a[72:75]", "a72","a73","a74","a75")
    MMA_ACC (c0, A4, "a[16:19]", "a16","a17","a18","a19")
    MMA_ACC (c1, A4, "a[36:39]", "a36","a37","a38","a39")
    MMA_ACC (c2, A4, "a[56:59]", "a56","a57","a58","a59")
    MMA_ACC (c3, A4, "a[76:79]", "a76","a77","a78","a79")
    asm volatile("s_nop 7\n\ts_nop 7" ::: );   // MFMA->VALU-read hazard cover

    {
      float* g0 = &gh[crow*516 + (wv   )*16 + ccol];
      float* g1 = &gh[crow*516 + (wv+ 8)*16 + ccol];
      float* g2 = &gh[crow*516 + (wv+16)*16 + ccol];
      float* g3 = &gh[crow*516 + (wv+24)*16 + ccol];
      g0[0]=c0[0]; g0[516]=c0[1]; g0[1032]=c0[2]; g0[1548]=c0[3];
      g1[0]=c1[0]; g1[516]=c1[1]; g1[1032]=c1[2]; g1[1548]=c1[3];
      g2[0]=c2[0]; g2[516]=c2[1]; g2[1032]=c2[2]; g2[1548]=c2[3];
      g3[0]=c3[0]; g3[516]=c3[1]; g3[1032]=c3[2]; g3[1548]=c3[3];
    }
    __syncthreads();

    // gate phase: gh_total[b][c] = C[b][c] (hi rows) + C[8+b][c] (lo rows)
    {
      float r = sigmoidf_(gr0 + gh[b0*516+u0]        + gh[(8+b0)*516+u0]        + bhr0);
      float z = sigmoidf_(gz0 + gh[b0*516+NHID+u0]   + gh[(8+b0)*516+NHID+u0]   + bhz0);
      float n = tanhf_  (gn0 + r*(gh[b0*516+2*NHID+u0] + gh[(8+b0)*516+2*NHID+u0] + bhn0));
      float hold = h_f32[b0*152+u0];
      float hn = (1.f - z)*n + z*hold;
      h_f32[b0*152+u0] = hn;
      unsigned int ub = __float_as_uint(hn);
      unsigned int hi = (ub + 0x7FFFu + ((ub>>16)&1u)) >> 16;
      h_bf[b0*176+u0] = (unsigned short)hi;
      float lo = hn - __uint_as_float(hi<<16);
      unsigned int ul = __float_as_uint(lo);
      h_bf[(8+b0)*176+u0] = (unsigned short)((ul + 0x7FFFu + ((ul>>16)&1u)) >> 16);
    }
    {
      float r = sigmoidf_(gr1 + gh[b1*516+u1]        + gh[(8+b1)*516+u1]        + bhr1);
      float z = sigmoidf_(gz1 + gh[b1*516+NHID+u1]   + gh[(8+b1)*516+NHID+u1]   + bhz1);
      float n = tanhf_  (gn1 + r*(gh[b1*516+2*NHID+u1] + gh[(8+b1)*516+2*NHID+u1] + bhn1));
      float hold = h_f32[b1*152+u1];
      float hn = (1.f - z)*n + z*hold;
      h_f32[b1*152+u1] = hn;
      unsigned int ub = __float_as_uint(hn);
      unsigned int hi = (ub + 0x7FFFu + ((ub>>16)&1u)) >> 16;
      h_bf[b1*176+u1] = (unsigned short)hi;
      float lo = hn - __uint_as_float(hi<<16);
      unsigned int ul = __float_as_uint(lo);
      h_bf[(8+b1)*176+u1] = (unsigned short)((ul + 0x7FFFu + ((ul>>16)&1u)) >> 16);
    }
    if (v2){
      float r = sigmoidf_(gr2 + gh[b2*516+u2]        + gh[(8+b2)*516+u2]        + bhr2);
      float z = sigmoidf_(gz2 + gh[b2*516+NHID+u2]   + gh[(8+b2)*516+NHID+u2]   + bhz2);
      float n = tanhf_  (gn2 + r*(gh[b2*516+2*NHID+u2] + gh[(8+b2)*516+2*NHID+u2] + bhn2));
      float hold = h_f32[b2*152+u2];
      float hn = (1.f - z)*n + z*hold;
      h_f32[b2*152+u2] = hn;
      unsigned int ub = __float_as_uint(hn);
      unsigned int hi = (ub + 0x7FFFu + ((ub>>16)&1u)) >> 16;
      h_bf[b2*176+u2] = (unsigned short)hi;
      float lo = hn - __uint_as_float(hi<<16);
      unsigned int ul = __float_as_uint(lo);
      h_bf[(8+b2)*176+u2] = (unsigned short)((ul + 0x7FFFu + ((ul>>16)&1u)) >> 16);
    }
    __syncthreads();
  }

  out[b0*NHID + u0] = h_f32[b0*152 + u0];
  out[b1*NHID + u1] = h_f32[b1*152 + u1];
  if (v2) out[b2*NHID + u2] = h_f32[b2*152 + u2];
}

extern "C" void kernel_launch(void* const* d_in, const int* in_sizes, int n_in,
                              void* d_out, int out_size, void* d_ws, size_t ws_size,
                              hipStream_t stream){
  const float* x       = (const float*)d_in[0];
  const float* conv_w  = (const float*)d_in[1];
  const float* conv_b  = (const float*)d_in[2];
  const float* f_lin_w = (const float*)d_in[3];
  const float* f_lin_b = (const float*)d_in[4];
  const float* f_a     = (const float*)d_in[5];
  const float* f_bias  = (const float*)d_in[6];
  const float* t_lin_w = (const float*)d_in[7];
  const float* t_lin_b = (const float*)d_in[8];
  const float* t_a     = (const float*)d_in[9];
  const float* t_bias  = (const float*)d_in[10];
  const float* w_ih    = (const float*)d_in[11];
  const float* w_hh    = (const float*)d_in[12];
  const float* b_ih    = (const float*)d_in[13];
  const float* b_hh    = (const float*)d_in[14];

  float* ws      = (float*)d_ws;
  float* xc      = ws;               // 160000
  float* conv_wT = ws + 160000;      // 70000
  float* si_f    = ws + 230000;      // 320000
  float* sj_f    = ws + 550000;      // 320000
  float* h_featT = ws + 870000;      // 160000
  float* si_t    = ws + 1030000;     // 320000
  float* sj_t    = ws + 1350000;     // 320000
  float* h_temp  = ws + 1670000;     // 160000
  float* w_ihT   = ws + 1830000;     // 135000
  float* gi      = ws + 1965000;     // 720000
  float* BfragF  = ws + 2685000;     // 40960 dwords (16B-aligned offset)
                                     // total 2725960 floats ~= 10.9 MB

  prep_kernel<<<961, 256, 0, stream>>>(conv_w, w_ih, w_hh, conv_wT, w_ihT, (unsigned int*)BfragF);
  conv_kernel<<<(NB*NW*NK + 255)/256, 256, 0, stream>>>(x, conv_b, conv_wT, xc);
  fgat_sisj<<<NB*25, 512, 0, stream>>>(xc, f_lin_w, si_f, sj_f);
  tgat_sisj<<<NB*50, 256, 0, stream>>>(xc, t_lin_w, si_t, sj_t);
  fgat_attn<<<NB*NK, 128, 0, stream>>>(xc, si_f, sj_f, f_lin_b, f_a, f_bias, h_featT);
  tgat_attn<<<NB*NW, 256, 0, stream>>>(xc, si_t, sj_t, t_lin_b, t_a, t_bias, h_temp);
  gi_kernel<<<NB*25, 512, 0, stream>>>(xc, h_featT, h_temp, w_ihT, b_ih, gi);
  gru_kernel<<<1, 512, 0, stream>>>(gi, (const int4*)BfragF, b_hh, (float*)d_out);
}

// Round 7
// 420.933 us; speedup vs baseline: 1.1883x; 1.0326x over previous
//
#include <hip/hip_runtime.h>
#include <math.h>

#define NB   8
#define NW   200
#define NK   100
#define KSZ  7
#define NHID 150
#define NFE  400
#define NTE  200
#define NG   450   // 3*HID
#define NCIN 300   // 3*K
#define ALPHAC 0.2f

typedef __attribute__((ext_vector_type(8))) short bf8;
typedef __attribute__((ext_vector_type(4))) float f32x4;

__device__ __forceinline__ float sigmoidf_(float x){
  return 1.0f/(1.0f + __expf(-x));
}
__device__ __forceinline__ float tanhf_(float x){
  float xc = fminf(fmaxf(x, -15.f), 15.f);
  float e = __expf(2.f*xc);
  return (e - 1.f)/(e + 1.f);
}
__device__ __forceinline__ unsigned short f2bf(float f){
  unsigned int u = __float_as_uint(f);
  unsigned int r = u + 0x7FFFu + ((u>>16)&1u);
  return (unsigned short)(r>>16);
}

// ---------------- weight prep: conv transpose, w_ih transpose, w_hh -> MFMA B-fragments ----------------
// Bfrag layout: 32 N-tiles x 5 K-steps x 64 lanes x 4 dwords (8 bf16).
// Lane l, dword d: k0 = ks*32 + (l>>4)*8 + d*2 (pair k0,k0+1 packed lo|hi), col = tile*16 + (l&15).
// B[k][c] = w_hh[c*150 + k] (zero-padded k>=150, c>=450).
__global__ void prep_kernel(const float* conv_w, const float* w_ih, const float* w_hh,
                            float* conv_wT, float* w_ihT, unsigned int* Bfrag){
  int idx = blockIdx.x*256 + threadIdx.x;
  const int n1 = NK*NK*KSZ;      // 70000
  const int n2 = NG*NCIN;        // 135000
  const int n3 = 32*5*64*4;      // 40960 dwords
  if (idx < n1){
    int k = idx % NK; int it = idx / NK;       // it = i*KSZ + t
    int i = it / KSZ, t = it % KSZ;
    conv_wT[idx] = conv_w[(k*NK + i)*KSZ + t];
  } else if (idx < n1 + n2){
    int o = idx - n1; int g = o % NG; int c = o / NG;
    w_ihT[o] = w_ih[g*NCIN + c];
  } else if (idx < n1 + n2 + n3){
    int o = idx - n1 - n2;
    int n   = o / 1280;
    int rem = o % 1280;
    int ks  = rem / 256;
    int rem2= rem % 256;
    int l   = rem2 >> 2;
    int d   = rem2 & 3;
    int col = n*16 + (l & 15);
    int k0  = ks*32 + (l >> 4)*8 + d*2;
    unsigned short lo = 0, hi = 0;
    if (col < NG){
      if (k0     < NHID) lo = f2bf(w_hh[col*NHID + k0]);
      if (k0 + 1 < NHID) hi = f2bf(w_hh[col*NHID + k0 + 1]);
    }
    Bfrag[o] = ((unsigned int)hi << 16) | lo;
  }
}

// ---------------- conv1d + bias + relu -> xc (B,W,K) ----------------
__global__ void conv_kernel(const float* x, const float* conv_b, const float* conv_wT, float* xc){
  int idx = blockIdx.x*256 + threadIdx.x;
  if (idx >= NB*NW*NK) return;
  int k = idx % NK; int w = (idx/NK) % NW; int b = idx/(NK*NW);
  float acc = conv_b[k];
  const float* xb = x + b*NW*NK;
  for (int t = 0; t < KSZ; ++t){
    int ws = w + t - 3;
    if (ws < 0 || ws >= NW) continue;
    const float* xr = xb + ws*NK;
    const float* wr = conv_wT + t*NK + k;   // (i*KSZ+t)*NK + k
    #pragma unroll 4
    for (int i = 0; i < NK; ++i){
      acc += xr[i] * wr[i*KSZ*NK];
    }
  }
  xc[idx] = fmaxf(acc, 0.0f);
}

// ---------------- f-GAT si/sj: (B,K,FE), nodes=features, v[b,n,d]=xc[b,d,n] ----------------
__global__ void fgat_sisj(const float* xc, const float* f_lin_w, float* si, float* sj){
  __shared__ __align__(16) float vt[NW*4];
  int b = blockIdx.x / 25; int n0 = (blockIdx.x % 25)*4;
  int tid = threadIdx.x;
  for (int idx = tid; idx < NW*4; idx += 512){
    int d = idx >> 2, nn = idx & 3;
    vt[idx] = xc[(b*NW + d)*NK + n0 + nn];
  }
  __syncthreads();
  if (tid >= NFE) return;
  int e = tid;
  float a1[4] = {0,0,0,0}, a2[4] = {0,0,0,0};
  for (int d = 0; d < NW; ++d){
    float w1 = f_lin_w[d*NFE + e];
    float w2 = f_lin_w[(NW + d)*NFE + e];
    float4 v = *(const float4*)&vt[d*4];
    a1[0] += v.x*w1; a1[1] += v.y*w1; a1[2] += v.z*w1; a1[3] += v.w*w1;
    a2[0] += v.x*w2; a2[1] += v.y*w2; a2[2] += v.z*w2; a2[3] += v.w*w2;
  }
  #pragma unroll
  for (int nn = 0; nn < 4; ++nn){
    si[(b*NK + n0+nn)*NFE + e] = a1[nn];
    sj[(b*NK + n0+nn)*NFE + e] = a2[nn];
  }
}

// ---------------- t-GAT si/sj: (B,W,TE), nodes=time, v[b,n,d]=xc[b,n,d] ----------------
__global__ void tgat_sisj(const float* xc, const float* t_lin_w, float* si, float* sj){
  __shared__ __align__(16) float vt[NK*4];
  int b = blockIdx.x / 50; int n0 = (blockIdx.x % 50)*4;
  int tid = threadIdx.x;
  for (int idx = tid; idx < NK*4; idx += 256){
    int d = idx >> 2, nn = idx & 3;
    vt[idx] = xc[(b*NW + n0+nn)*NK + d];
  }
  __syncthreads();
  if (tid >= NTE) return;
  int e = tid;
  float a1[4] = {0,0,0,0}, a2[4] = {0,0,0,0};
  for (int d = 0; d < NK; ++d){
    float w1 = t_lin_w[d*NTE + e];
    float w2 = t_lin_w[(NK + d)*NTE + e];
    float4 v = *(const float4*)&vt[d*4];
    a1[0] += v.x*w1; a1[1] += v.y*w1; a1[2] += v.z*w1; a1[3] += v.w*w1;
    a2[0] += v.x*w2; a2[1] += v.y*w2; a2[2] += v.z*w2; a2[3] += v.w*w2;
  }
  #pragma unroll
  for (int nn = 0; nn < 4; ++nn){
    si[(b*NW + n0+nn)*NTE + e] = a1[nn];
    sj[(b*NW + n0+nn)*NTE + e] = a2[nn];
  }
}

// ---------------- f-GAT attention fused: e -> softmax -> sigmoid(attn@v) ----------------
// out written transposed into (B,W,K): h_featT[b,d,i]
__global__ void fgat_attn(const float* xc, const float* si, const float* sj,
                          const float* f_lin_b, const float* f_a, const float* f_bias,
                          float* h_featT){
  __shared__ float sib[NFE], av[NFE], attn[NK], red[128];
  int b = blockIdx.x / NK, i = blockIdx.x % NK;
  int tid = threadIdx.x;
  for (int e = tid; e < NFE; e += 128){
    sib[e] = si[(b*NK + i)*NFE + e] + f_lin_b[e];
    av[e]  = f_a[e];
  }
  __syncthreads();
  float ej = -1e30f;
  if (tid < NK){
    const float* sjr = sj + (b*NK + tid)*NFE;
    float acc = 0.f;
    for (int e = 0; e < NFE; ++e){
      float tv = sib[e] + sjr[e];
      float lk = fmaxf(tv, 0.f) + ALPHAC*fminf(tv, 0.f);
      acc += av[e]*lk;
    }
    ej = acc + f_bias[i*NK + tid];
  }
  red[tid] = ej; __syncthreads();
  for (int s = 64; s > 0; s >>= 1){ if (tid < s) red[tid] = fmaxf(red[tid], red[tid+s]); __syncthreads(); }
  float m = red[0]; __syncthreads();
  float ex = (tid < NK) ? __expf(ej - m) : 0.f;
  red[tid] = ex; __syncthreads();
  for (int s = 64; s > 0; s >>= 1){ if (tid < s) red[tid] += red[tid+s]; __syncthreads(); }
  float denom = red[0];
  if (tid < NK) attn[tid] = ex / denom;
  __syncthreads();
  for (int d = tid; d < NW; d += 128){
    const float* xr = xc + (b*NW + d)*NK;    // v[b,j,d] = xc[b,d,j]
    float acc = 0.f;
    for (int j = 0; j < NK; ++j) acc += attn[j]*xr[j];
    h_featT[(b*NW + d)*NK + i] = sigmoidf_(acc);
  }
}

// ---------------- t-GAT attention fused -> h_temp (B,W,K) ----------------
__global__ void tgat_attn(const float* xc, const float* si, const float* sj,
                          const float* t_lin_b, const float* t_a, const float* t_bias,
                          float* h_temp){
  __shared__ float sib[NTE], av[NTE], attn[NW], red[256];
  int b = blockIdx.x / NW, i = blockIdx.x % NW;
  int tid = threadIdx.x;
  for (int e = tid; e < NTE; e += 256){
    sib[e] = si[(b*NW + i)*NTE + e] + t_lin_b[e];
    av[e]  = t_a[e];
  }
  __syncthreads();
  float ej = -1e30f;
  if (tid < NW){
    const float* sjr = sj + (b*NW + tid)*NTE;
    float acc = 0.f;
    for (int e = 0; e < NTE; ++e){
      float tv = sib[e] + sjr[e];
      float lk = fmaxf(tv, 0.f) + ALPHAC*fminf(tv, 0.f);
      acc += av[e]*lk;
    }
    ej = acc + t_bias[i*NW + tid];
  }
  red[tid] = ej; __syncthreads();
  for (int s = 128; s > 0; s >>= 1){ if (tid < s) red[tid] = fmaxf(red[tid], red[tid+s]); __syncthreads(); }
  float m = red[0]; __syncthreads();
  float ex = (tid < NW) ? __expf(ej - m) : 0.f;
  red[tid] = ex; __syncthreads();
  for (int s = 128; s > 0; s >>= 1){ if (tid < s) red[tid] += red[tid+s]; __syncthreads(); }
  float denom = red[0];
  if (tid < NW) attn[tid] = ex / denom;
  __syncthreads();
  for (int d = tid; d < NK; d += 256){
    float acc = 0.f;
    for (int j = 0; j < NW; ++j) acc += attn[j]*xc[(b*NW + j)*NK + d];
    h_temp[(b*NW + i)*NK + d] = sigmoidf_(acc);
  }
}

// ---------------- gi = h_cat @ w_ih^T + b_ih, layout (t, b, g) ----------------
__global__ void gi_kernel(const float* xc, const float* h_featT, const float* h_temp,
                          const float* w_ihT, const float* b_ih, float* gi){
  __shared__ __align__(16) float hc[NCIN*8];   // [c][tt], stride 8
  int b = blockIdx.x / 25; int t0 = (blockIdx.x % 25)*8;
  int tid = threadIdx.x;
  for (int idx = tid; idx < NCIN*8; idx += 512){
    int tt = idx / NCIN; int c = idx % NCIN;
    int base = (b*NW + t0 + tt)*NK;
    float v;
    if (c < NK)        v = xc[base + c];
    else if (c < 2*NK) v = h_featT[base + c - NK];
    else               v = h_temp[base + c - 2*NK];
    hc[c*8 + tt] = v;
  }
  __syncthreads();
  if (tid >= NG) return;
  int g = tid;
  float bi = b_ih[g];
  float acc[8];
  #pragma unroll
  for (int tt = 0; tt < 8; ++tt) acc[tt] = bi;
  for (int c = 0; c < NCIN; ++c){
    float wv = w_ihT[c*NG + g];
    float4 h0 = *(const float4*)&hc[c*8];
    float4 h1 = *(const float4*)&hc[c*8+4];
    acc[0] += h0.x*wv; acc[1] += h0.y*wv; acc[2] += h0.z*wv; acc[3] += h0.w*wv;
    acc[4] += h1.x*wv; acc[5] += h1.y*wv; acc[6] += h1.z*wv; acc[7] += h1.w*wv;
  }
  #pragma unroll
  for (int tt = 0; tt < 8; ++tt)
    gi[((t0+tt)*NB + b)*NG + g] = acc[tt];
}

// ---------------- sequential GRU: one block (1024 thr / 16 waves), MFMA + AGPR weights ----------------
// Round-6 diagnosis: at 512 thr the gate phase serialized 3 triples/thread
// (~49% VALU-busy on the one CU) with only 2 waves/SIMD to hide latency.
// Now: 16 waves x 2 N-tiles (10 MFMA, AGPRs a0..a39), gate phase ~1
// triple/thread, 4 waves/SIMD. AGPR stash unchanged (rounds 4/5: allocator
// remats or spills any VGPR-resident loop-invariant fragment array).
#define STASH(B0,B1,B2,B3, FR) { \
  int4 wq = Bq[(FR)*64 + lane]; \
  asm volatile("v_accvgpr_write_b32 " B0 ", %0\n\t" \
               "v_accvgpr_write_b32 " B1 ", %1\n\t" \
               "v_accvgpr_write_b32 " B2 ", %2\n\t" \
               "v_accvgpr_write_b32 " B3 ", %3" \
               :: "v"(wq.x), "v"(wq.y), "v"(wq.z), "v"(wq.w) \
               : B0, B1, B2, B3); }
#define MMA_INIT(ACC, AF, BR, C0,C1,C2,C3) \
  asm volatile("v_mfma_f32_16x16x32_bf16 %0, %1, " BR ", 0" \
               : "=v"(ACC) : "v"(AF) : C0,C1,C2,C3);
#define MMA_ACC(ACC, AF, BR, C0,C1,C2,C3) \
  asm volatile("v_mfma_f32_16x16x32_bf16 %0, %1, " BR ", %0" \
               : "+v"(ACC) : "v"(AF) : C0,C1,C2,C3);

__global__ void __launch_bounds__(1024, 4) gru_kernel(const float* gi, const int4* Bq,
                                                      const float* b_hh, float* out){
  __shared__ __align__(16) unsigned short h_bf[16*176];   // rows 0-7 hi, 8-15 lo
  __shared__ __align__(16) float h_f32[8*152];
  __shared__ __align__(16) float gh[16*516];
  int tid = threadIdx.x;
  int lane = tid & 63;
  int wv = tid >> 6;            // wave 0..15; owns N-tiles wv and wv+16
  int agrp = lane >> 4;         // 0..3
  int arow = lane & 15;
  int crow = agrp*4;
  int ccol = arow;

  // gate-phase assignments: every thread has p0 = tid (<1200 always);
  // threads 0..175 also handle p1 = tid + 1024.
  int p0 = tid;
  int b0 = p0/NHID, u0 = p0%NHID;
  bool v1 = (tid < 176);
  int p1 = tid + 1024;
  int b1 = v1 ? p1/NHID : 0, u1 = v1 ? p1%NHID : 0;
  float bhr0 = b_hh[u0], bhz0 = b_hh[NHID+u0], bhn0 = b_hh[2*NHID+u0];
  float bhr1 = b_hh[u1], bhz1 = b_hh[NHID+u1], bhn1 = b_hh[2*NHID+u1];

  // stash the 10 B-fragments (tiles wv, wv+16; 5 K-steps) in a0..a39
  STASH("a0","a1","a2","a3",     (wv)*5+0)
  STASH("a4","a5","a6","a7",     (wv)*5+1)
  STASH("a8","a9","a10","a11",   (wv)*5+2)
  STASH("a12","a13","a14","a15", (wv)*5+3)
  STASH("a16","a17","a18","a19", (wv)*5+4)
  STASH("a20","a21","a22","a23", (wv+16)*5+0)
  STASH("a24","a25","a26","a27", (wv+16)*5+1)
  STASH("a28","a29","a30","a31", (wv+16)*5+2)
  STASH("a32","a33","a34","a35", (wv+16)*5+3)
  STASH("a36","a37","a38","a39", (wv+16)*5+4)

  for (int i = tid; i < 16*176; i += 1024) h_bf[i] = 0;
  for (int i = tid; i < 8*152;  i += 1024) h_f32[i] = 0.f;
  __syncthreads();

  const bf8* HB = (const bf8*)h_bf;
  int abase = arow*22 + agrp;   // bf8 units; row stride 176 bf16 = 22 bf8

  for (int t = 0; t < NW; ++t){
    // prefetch this step's gi (consumed after the barrier)
    const float* gt = gi + t*NB*NG;
    float gr0 = gt[b0*NG+u0], gz0 = gt[b0*NG+NHID+u0], gn0 = gt[b0*NG+2*NHID+u0];
    float gr1 = 0.f, gz1 = 0.f, gn1 = 0.f;
    if (v1){ gr1 = gt[b1*NG+u1]; gz1 = gt[b1*NG+NHID+u1]; gn1 = gt[b1*NG+2*NHID+u1]; }

    // A fragments: rows 0-7 hi(batch), 8-15 lo(batch); shared by this wave's 2 tiles
    bf8 A0 = HB[abase],    A1 = HB[abase+4],  A2 = HB[abase+8],
        A3 = HB[abase+12], A4 = HB[abase+16];

    f32x4 c0, c1;
    MMA_INIT(c0, A0, "a[0:3]",   "a0","a1","a2","a3")
    MMA_INIT(c1, A0, "a[20:23]", "a20","a21","a22","a23")
    MMA_ACC (c0, A1, "a[4:7]",   "a4","a5","a6","a7")
    MMA_ACC (c1, A1, "a[24:27]", "a24","a25","a26","a27")
    MMA_ACC (c0, A2, "a[8:11]",  "a8","a9","a10","a11")
    MMA_ACC (c1, A2, "a[28:31]", "a28","a29","a30","a31")
    MMA_ACC (c0, A3, "a[12:15]", "a12","a13","a14","a15")
    MMA_ACC (c1, A3, "a[32:35]", "a32","a33","a34","a35")
    MMA_ACC (c0, A4, "a[16:19]", "a16","a17","a18","a19")
    MMA_ACC (c1, A4, "a[36:39]", "a36","a37","a38","a39")
    asm volatile("s_nop 7\n\ts_nop 7" ::: );   // MFMA->VALU-read hazard cover

    {
      float* g0 = &gh[crow*516 + (wv   )*16 + ccol];
      float* g1 = &gh[crow*516 + (wv+16)*16 + ccol];
      g0[0]=c0[0]; g0[516]=c0[1]; g0[1032]=c0[2]; g0[1548]=c0[3];
      g1[0]=c1[0]; g1[516]=c1[1]; g1[1032]=c1[2]; g1[1548]=c1[3];
    }
    __syncthreads();

    // gate phase: gh_total[b][c] = C[b][c] (hi rows) + C[8+b][c] (lo rows)
    {
      float r = sigmoidf_(gr0 + gh[b0*516+u0]        + gh[(8+b0)*516+u0]        + bhr0);
      float z = sigmoidf_(gz0 + gh[b0*516+NHID+u0]   + gh[(8+b0)*516+NHID+u0]   + bhz0);
      float n = tanhf_  (gn0 + r*(gh[b0*516+2*NHID+u0] + gh[(8+b0)*516+2*NHID+u0] + bhn0));
      float hold = h_f32[b0*152+u0];
      float hn = (1.f - z)*n + z*hold;
      h_f32[b0*152+u0] = hn;
      unsigned int ub = __float_as_uint(hn);
      unsigned int hi = (ub + 0x7FFFu + ((ub>>16)&1u)) >> 16;
      h_bf[b0*176+u0] = (unsigned short)hi;
      float lo = hn - __uint_as_float(hi<<16);
      unsigned int ul = __float_as_uint(lo);
      h_bf[(8+b0)*176+u0] = (unsigned short)((ul + 0x7FFFu + ((ul>>16)&1u)) >> 16);
    }
    if (v1){
      float r = sigmoidf_(gr1 + gh[b1*516+u1]        + gh[(8+b1)*516+u1]        + bhr1);
      float z = sigmoidf_(gz1 + gh[b1*516+NHID+u1]   + gh[(8+b1)*516+NHID+u1]   + bhz1);
      float n = tanhf_  (gn1 + r*(gh[b1*516+2*NHID+u1] + gh[(8+b1)*516+2*NHID+u1] + bhn1));
      float hold = h_f32[b1*152+u1];
      float hn = (1.f - z)*n + z*hold;
      h_f32[b1*152+u1] = hn;
      unsigned int ub = __float_as_uint(hn);
      unsigned int hi = (ub + 0x7FFFu + ((ub>>16)&1u)) >> 16;
      h_bf[b1*176+u1] = (unsigned short)hi;
      float lo = hn - __uint_as_float(hi<<16);
      unsigned int ul = __float_as_uint(lo);
      h_bf[(8+b1)*176+u1] = (unsigned short)((ul + 0x7FFFu + ((ul>>16)&1u)) >> 16);
    }
    __syncthreads();
  }

  out[b0*NHID + u0] = h_f32[b0*152 + u0];
  if (v1) out[b1*NHID + u1] = h_f32[b1*152 + u1];
}

extern "C" void kernel_launch(void* const* d_in, const int* in_sizes, int n_in,
                              void* d_out, int out_size, void* d_ws, size_t ws_size,
                              hipStream_t stream){
  const float* x       = (const float*)d_in[0];
  const float* conv_w  = (const float*)d_in[1];
  const float* conv_b  = (const float*)d_in[2];
  const float* f_lin_w = (const float*)d_in[3];
  const float* f_lin_b = (const float*)d_in[4];
  const float* f_a     = (const float*)d_in[5];
  const float* f_bias  = (const float*)d_in[6];
  const float* t_lin_w = (const float*)d_in[7];
  const float* t_lin_b = (const float*)d_in[8];
  const float* t_a     = (const float*)d_in[9];
  const float* t_bias  = (const float*)d_in[10];
  const float* w_ih    = (const float*)d_in[11];
  const float* w_hh    = (const float*)d_in[12];
  const float* b_ih    = (const float*)d_in[13];
  const float* b_hh    = (const float*)d_in[14];

  float* ws      = (float*)d_ws;
  float* xc      = ws;               // 160000
  float* conv_wT = ws + 160000;      // 70000
  float* si_f    = ws + 230000;      // 320000
  float* sj_f    = ws + 550000;      // 320000
  float* h_featT = ws + 870000;      // 160000
  float* si_t    = ws + 1030000;     // 320000
  float* sj_t    = ws + 1350000;     // 320000
  float* h_temp  = ws + 1670000;     // 160000
  float* w_ihT   = ws + 1830000;     // 135000
  float* gi      = ws + 1965000;     // 720000
  float* BfragF  = ws + 2685000;     // 40960 dwords (16B-aligned offset)
                                     // total 2725960 floats ~= 10.9 MB

  prep_kernel<<<961, 256, 0, stream>>>(conv_w, w_ih, w_hh, conv_wT, w_ihT, (unsigned int*)BfragF);
  conv_kernel<<<(NB*NW*NK + 255)/256, 256, 0, stream>>>(x, conv_b, conv_wT, xc);
  fgat_sisj<<<NB*25, 512, 0, stream>>>(xc, f_lin_w, si_f, sj_f);
  tgat_sisj<<<NB*50, 256, 0, stream>>>(xc, t_lin_w, si_t, sj_t);
  fgat_attn<<<NB*NK, 128, 0, stream>>>(xc, si_f, sj_f, f_lin_b, f_a, f_bias, h_featT);
  tgat_attn<<<NB*NW, 256, 0, stream>>>(xc, si_t, sj_t, t_lin_b, t_a, t_bias, h_temp);
  gi_kernel<<<NB*25, 512, 0, stream>>>(xc, h_featT, h_temp, w_ihT, b_ih, gi);
  gru_kernel<<<1, 1024, 0, stream>>>(gi, (const int4*)BfragF, b_hh, (float*)d_out);
}

// Round 8
// 409.486 us; speedup vs baseline: 1.2216x; 1.0280x over previous
//
#include <hip/hip_runtime.h>
#include <math.h>

#define NB   8
#define NW   200
#define NK   100
#define KSZ  7
#define NHID 150
#define NFE  400
#define NTE  200
#define NG   450   // 3*HID
#define NCIN 300   // 3*K
#define ALPHAC 0.2f

typedef __attribute__((ext_vector_type(8))) short bf8;
typedef __attribute__((ext_vector_type(4))) float f32x4;

__device__ __forceinline__ float sigmoidf_(float x){
  return 1.0f/(1.0f + __expf(-x));
}
__device__ __forceinline__ float tanhf_(float x){
  float xc = fminf(fmaxf(x, -15.f), 15.f);
  float e = __expf(2.f*xc);
  return (e - 1.f)/(e + 1.f);
}
__device__ __forceinline__ unsigned short f2bf(float f){
  unsigned int u = __float_as_uint(f);
  unsigned int r = u + 0x7FFFu + ((u>>16)&1u);
  return (unsigned short)(r>>16);
}

// ---------------- weight prep: conv transpose, w_ih transpose, w_hh -> MFMA B-fragments ----------------
// Bfrag layout: 32 N-tiles x 5 K-steps x 64 lanes x 4 dwords (8 bf16).
// Lane l, dword d: k0 = ks*32 + (l>>4)*8 + d*2 (pair k0,k0+1 packed lo|hi), col = tile*16 + (l&15).
// B[k][c] = w_hh[c*150 + k] (zero-padded k>=150, c>=450).
__global__ void prep_kernel(const float* conv_w, const float* w_ih, const float* w_hh,
                            float* conv_wT, float* w_ihT, unsigned int* Bfrag){
  int idx = blockIdx.x*256 + threadIdx.x;
  const int n1 = NK*NK*KSZ;      // 70000
  const int n2 = NG*NCIN;        // 135000
  const int n3 = 32*5*64*4;      // 40960 dwords
  if (idx < n1){
    int k = idx % NK; int it = idx / NK;       // it = i*KSZ + t
    int i = it / KSZ, t = it % KSZ;
    conv_wT[idx] = conv_w[(k*NK + i)*KSZ + t];
  } else if (idx < n1 + n2){
    int o = idx - n1; int g = o % NG; int c = o / NG;
    w_ihT[o] = w_ih[g*NCIN + c];
  } else if (idx < n1 + n2 + n3){
    int o = idx - n1 - n2;
    int n   = o / 1280;
    int rem = o % 1280;
    int ks  = rem / 256;
    int rem2= rem % 256;
    int l   = rem2 >> 2;
    int d   = rem2 & 3;
    int col = n*16 + (l & 15);
    int k0  = ks*32 + (l >> 4)*8 + d*2;
    unsigned short lo = 0, hi = 0;
    if (col < NG){
      if (k0     < NHID) lo = f2bf(w_hh[col*NHID + k0]);
      if (k0 + 1 < NHID) hi = f2bf(w_hh[col*NHID + k0 + 1]);
    }
    Bfrag[o] = ((unsigned int)hi << 16) | lo;
  }
}

// ---------------- conv1d + bias + relu -> xc (B,W,K) ----------------
__global__ void conv_kernel(const float* x, const float* conv_b, const float* conv_wT, float* xc){
  int idx = blockIdx.x*256 + threadIdx.x;
  if (idx >= NB*NW*NK) return;
  int k = idx % NK; int w = (idx/NK) % NW; int b = idx/(NK*NW);
  float acc = conv_b[k];
  const float* xb = x + b*NW*NK;
  for (int t = 0; t < KSZ; ++t){
    int ws = w + t - 3;
    if (ws < 0 || ws >= NW) continue;
    const float* xr = xb + ws*NK;
    const float* wr = conv_wT + t*NK + k;   // (i*KSZ+t)*NK + k
    #pragma unroll 4
    for (int i = 0; i < NK; ++i){
      acc += xr[i] * wr[i*KSZ*NK];
    }
  }
  xc[idx] = fmaxf(acc, 0.0f);
}

// ---------------- f-GAT si/sj: (B,K,FE), nodes=features, v[b,n,d]=xc[b,d,n] ----------------
__global__ void fgat_sisj(const float* xc, const float* f_lin_w, float* si, float* sj){
  __shared__ __align__(16) float vt[NW*4];
  int b = blockIdx.x / 25; int n0 = (blockIdx.x % 25)*4;
  int tid = threadIdx.x;
  for (int idx = tid; idx < NW*4; idx += 512){
    int d = idx >> 2, nn = idx & 3;
    vt[idx] = xc[(b*NW + d)*NK + n0 + nn];
  }
  __syncthreads();
  if (tid >= NFE) return;
  int e = tid;
  float a1[4] = {0,0,0,0}, a2[4] = {0,0,0,0};
  for (int d = 0; d < NW; ++d){
    float w1 = f_lin_w[d*NFE + e];
    float w2 = f_lin_w[(NW + d)*NFE + e];
    float4 v = *(const float4*)&vt[d*4];
    a1[0] += v.x*w1; a1[1] += v.y*w1; a1[2] += v.z*w1; a1[3] += v.w*w1;
    a2[0] += v.x*w2; a2[1] += v.y*w2; a2[2] += v.z*w2; a2[3] += v.w*w2;
  }
  #pragma unroll
  for (int nn = 0; nn < 4; ++nn){
    si[(b*NK + n0+nn)*NFE + e] = a1[nn];
    sj[(b*NK + n0+nn)*NFE + e] = a2[nn];
  }
}

// ---------------- t-GAT si/sj: (B,W,TE), nodes=time, v[b,n,d]=xc[b,n,d] ----------------
__global__ void tgat_sisj(const float* xc, const float* t_lin_w, float* si, float* sj){
  __shared__ __align__(16) float vt[NK*4];
  int b = blockIdx.x / 50; int n0 = (blockIdx.x % 50)*4;
  int tid = threadIdx.x;
  for (int idx = tid; idx < NK*4; idx += 256){
    int d = idx >> 2, nn = idx & 3;
    vt[idx] = xc[(b*NW + n0+nn)*NK + d];
  }
  __syncthreads();
  if (tid >= NTE) return;
  int e = tid;
  float a1[4] = {0,0,0,0}, a2[4] = {0,0,0,0};
  for (int d = 0; d < NK; ++d){
    float w1 = t_lin_w[d*NTE + e];
    float w2 = t_lin_w[(NK + d)*NTE + e];
    float4 v = *(const float4*)&vt[d*4];
    a1[0] += v.x*w1; a1[1] += v.y*w1; a1[2] += v.z*w1; a1[3] += v.w*w1;
    a2[0] += v.x*w2; a2[1] += v.y*w2; a2[2] += v.z*w2; a2[3] += v.w*w2;
  }
  #pragma unroll
  for (int nn = 0; nn < 4; ++nn){
    si[(b*NW + n0+nn)*NTE + e] = a1[nn];
    sj[(b*NW + n0+nn)*NTE + e] = a2[nn];
  }
}

// ---------------- f-GAT attention fused: e -> softmax -> sigmoid(attn@v) ----------------
// out written transposed into (B,W,K): h_featT[b,d,i]
__global__ void fgat_attn(const float* xc, const float* si, const float* sj,
                          const float* f_lin_b, const float* f_a, const float* f_bias,
                          float* h_featT){
  __shared__ float sib[NFE], av[NFE], attn[NK], red[128];
  int b = blockIdx.x / NK, i = blockIdx.x % NK;
  int tid = threadIdx.x;
  for (int e = tid; e < NFE; e += 128){
    sib[e] = si[(b*NK + i)*NFE + e] + f_lin_b[e];
    av[e]  = f_a[e];
  }
  __syncthreads();
  float ej = -1e30f;
  if (tid < NK){
    const float* sjr = sj + (b*NK + tid)*NFE;
    float acc = 0.f;
    for (int e = 0; e < NFE; ++e){
      float tv = sib[e] + sjr[e];
      float lk = fmaxf(tv, 0.f) + ALPHAC*fminf(tv, 0.f);
      acc += av[e]*lk;
    }
    ej = acc + f_bias[i*NK + tid];
  }
  red[tid] = ej; __syncthreads();
  for (int s = 64; s > 0; s >>= 1){ if (tid < s) red[tid] = fmaxf(red[tid], red[tid+s]); __syncthreads(); }
  float m = red[0]; __syncthreads();
  float ex = (tid < NK) ? __expf(ej - m) : 0.f;
  red[tid] = ex; __syncthreads();
  for (int s = 64; s > 0; s >>= 1){ if (tid < s) red[tid] += red[tid+s]; __syncthreads(); }
  float denom = red[0];
  if (tid < NK) attn[tid] = ex / denom;
  __syncthreads();
  for (int d = tid; d < NW; d += 128){
    const float* xr = xc + (b*NW + d)*NK;    // v[b,j,d] = xc[b,d,j]
    float acc = 0.f;
    for (int j = 0; j < NK; ++j) acc += attn[j]*xr[j];
    h_featT[(b*NW + d)*NK + i] = sigmoidf_(acc);
  }
}

// ---------------- t-GAT attention fused -> h_temp (B,W,K) ----------------
__global__ void tgat_attn(const float* xc, const float* si, const float* sj,
                          const float* t_lin_b, const float* t_a, const float* t_bias,
                          float* h_temp){
  __shared__ float sib[NTE], av[NTE], attn[NW], red[256];
  int b = blockIdx.x / NW, i = blockIdx.x % NW;
  int tid = threadIdx.x;
  for (int e = tid; e < NTE; e += 256){
    sib[e] = si[(b*NW + i)*NTE + e] + t_lin_b[e];
    av[e]  = t_a[e];
  }
  __syncthreads();
  float ej = -1e30f;
  if (tid < NW){
    const float* sjr = sj + (b*NW + tid)*NTE;
    float acc = 0.f;
    for (int e = 0; e < NTE; ++e){
      float tv = sib[e] + sjr[e];
      float lk = fmaxf(tv, 0.f) + ALPHAC*fminf(tv, 0.f);
      acc += av[e]*lk;
    }
    ej = acc + t_bias[i*NW + tid];
  }
  red[tid] = ej; __syncthreads();
  for (int s = 128; s > 0; s >>= 1){ if (tid < s) red[tid] = fmaxf(red[tid], red[tid+s]); __syncthreads(); }
  float m = red[0]; __syncthreads();
  float ex = (tid < NW) ? __expf(ej - m) : 0.f;
  red[tid] = ex; __syncthreads();
  for (int s = 128; s > 0; s >>= 1){ if (tid < s) red[tid] += red[tid+s]; __syncthreads(); }
  float denom = red[0];
  if (tid < NW) attn[tid] = ex / denom;
  __syncthreads();
  for (int d = tid; d < NK; d += 256){
    float acc = 0.f;
    for (int j = 0; j < NW; ++j) acc += attn[j]*xc[(b*NW + j)*NK + d];
    h_temp[(b*NW + i)*NK + d] = sigmoidf_(acc);
  }
}

// ---------------- gi = h_cat @ w_ih^T + b_ih, layout (t, b, g) ----------------
__global__ void gi_kernel(const float* xc, const float* h_featT, const float* h_temp,
                          const float* w_ihT, const float* b_ih, float* gi){
  __shared__ __align__(16) float hc[NCIN*8];   // [c][tt], stride 8
  int b = blockIdx.x / 25; int t0 = (blockIdx.x % 25)*8;
  int tid = threadIdx.x;
  for (int idx = tid; idx < NCIN*8; idx += 512){
    int tt = idx / NCIN; int c = idx % NCIN;
    int base = (b*NW + t0 + tt)*NK;
    float v;
    if (c < NK)        v = xc[base + c];
    else if (c < 2*NK) v = h_featT[base + c - NK];
    else               v = h_temp[base + c - 2*NK];
    hc[c*8 + tt] = v;
  }
  __syncthreads();
  if (tid >= NG) return;
  int g = tid;
  float bi = b_ih[g];
  float acc[8];
  #pragma unroll
  for (int tt = 0; tt < 8; ++tt) acc[tt] = bi;
  for (int c = 0; c < NCIN; ++c){
    float wv = w_ihT[c*NG + g];
    float4 h0 = *(const float4*)&hc[c*8];
    float4 h1 = *(const float4*)&hc[c*8+4];
    acc[0] += h0.x*wv; acc[1] += h0.y*wv; acc[2] += h0.z*wv; acc[3] += h0.w*wv;
    acc[4] += h1.x*wv; acc[5] += h1.y*wv; acc[6] += h1.z*wv; acc[7] += h1.w*wv;
  }
  #pragma unroll
  for (int tt = 0; tt < 8; ++tt)
    gi[((t0+tt)*NB + b)*NG + g] = acc[tt];
}

// ---------------- sequential GRU: one block (768 thr / 12 waves), MFMA + AGPR weights ----------------
// Round-7 diagnosis: LDS-PIPE THROUGHPUT bound (~2900 cyc/step of serialized
// DS instructions). This version cuts LDS instrs ~2.3x:
//  - 8 MFMA waves x 4 tiles (A-reads 80->40 instr/step)
//  - A rows interleaved (hi0,lo0,hi1,lo1,..): hi/lo C-rows are adjacent regs
//    of the SAME lane -> fold = 2 VALU adds; gh halves to [col][8];
//    C-writes 128 b32 -> 32 b64; gate reads 6 -> 3 b32 per triple
//  - h state registerized (fixed thread owns each (b,u) triple forever)
//  - h_bf row stride 184 (kills 4-way bank conflict on ds_read_b128)
//  - gi prefetched one full step ahead (HBM latency ~900 cyc covered)
#define STASH(B0,B1,B2,B3, FR) { \
  int4 wq = Bq[(FR)*64 + lane]; \
  asm volatile("v_accvgpr_write_b32 " B0 ", %0\n\t" \
               "v_accvgpr_write_b32 " B1 ", %1\n\t" \
               "v_accvgpr_write_b32 " B2 ", %2\n\t" \
               "v_accvgpr_write_b32 " B3 ", %3" \
               :: "v"(wq.x), "v"(wq.y), "v"(wq.z), "v"(wq.w) \
               : B0, B1, B2, B3); }
#define MMA_INIT(ACC, AF, BR, C0,C1,C2,C3) \
  asm volatile("v_mfma_f32_16x16x32_bf16 %0, %1, " BR ", 0" \
               : "=v"(ACC) : "v"(AF) : C0,C1,C2,C3);
#define MMA_ACC(ACC, AF, BR, C0,C1,C2,C3) \
  asm volatile("v_mfma_f32_16x16x32_bf16 %0, %1, " BR ", %0" \
               : "+v"(ACC) : "v"(AF) : C0,C1,C2,C3);

__global__ void __launch_bounds__(768) gru_kernel(const float* gi, const int4* Bq,
                                                  const float* b_hh, float* out){
  __shared__ __align__(16) unsigned short h_bf[16*184];  // row 2b=hi(b), 2b+1=lo(b); k-pad zeros
  __shared__ __align__(16) float gh[512*10];             // [col][8 batches + 2 pad], hi+lo folded
  int tid = threadIdx.x;
  int lane = tid & 63;
  int wv = tid >> 6;            // 0..11; waves 0..7 do MFMA (tiles wv, wv+8, wv+16, wv+24)
  int agrp = lane >> 4;         // 0..3
  int arow = lane & 15;

  // gate assignments: p0 = tid (all 768), p1 = tid+768 (tid<432)
  int b0 = tid/NHID, u0 = tid%NHID;
  bool v1 = (tid < 432);
  int p1 = tid + 768;
  int b1 = v1 ? p1/NHID : 0, u1 = v1 ? p1%NHID : 0;
  float bhr0 = b_hh[u0], bhz0 = b_hh[NHID+u0], bhn0 = b_hh[2*NHID+u0];
  float bhr1 = b_hh[u1], bhz1 = b_hh[NHID+u1], bhn1 = b_hh[2*NHID+u1];

  if (wv < 8){
    STASH("a0","a1","a2","a3",     (wv)*5+0)
    STASH("a4","a5","a6","a7",     (wv)*5+1)
    STASH("a8","a9","a10","a11",   (wv)*5+2)
    STASH("a12","a13","a14","a15", (wv)*5+3)
    STASH("a16","a17","a18","a19", (wv)*5+4)
    STASH("a20","a21","a22","a23", (wv+8)*5+0)
    STASH("a24","a25","a26","a27", (wv+8)*5+1)
    STASH("a28","a29","a30","a31", (wv+8)*5+2)
    STASH("a32","a33","a34","a35", (wv+8)*5+3)
    STASH("a36","a37","a38","a39", (wv+8)*5+4)
    STASH("a40","a41","a42","a43", (wv+16)*5+0)
    STASH("a44","a45","a46","a47", (wv+16)*5+1)
    STASH("a48","a49","a50","a51", (wv+16)*5+2)
    STASH("a52","a53","a54","a55", (wv+16)*5+3)
    STASH("a56","a57","a58","a59", (wv+16)*5+4)
    STASH("a60","a61","a62","a63", (wv+24)*5+0)
    STASH("a64","a65","a66","a67", (wv+24)*5+1)
    STASH("a68","a69","a70","a71", (wv+24)*5+2)
    STASH("a72","a73","a74","a75", (wv+24)*5+3)
    STASH("a76","a77","a78","a79", (wv+24)*5+4)
  }

  for (int i = tid; i < 16*184; i += 768) h_bf[i] = 0;
  __syncthreads();

  const bf8* HB = (const bf8*)h_bf;
  int abase = arow*23 + agrp;   // bf8(16B) units; row stride 184 bf16 = 23 bf8

  float hold0 = 0.f, hold1 = 0.f;

  // gi for step 0 (cur), prefetch pipeline
  float cr0, cz0, cn0, cr1 = 0.f, cz1 = 0.f, cn1 = 0.f;
  {
    const float* g0 = gi + b0*NG;
    cr0 = g0[u0]; cz0 = g0[NHID+u0]; cn0 = g0[2*NHID+u0];
    if (v1){
      const float* g1 = gi + b1*NG;
      cr1 = g1[u1]; cz1 = g1[NHID+u1]; cn1 = g1[2*NHID+u1];
    }
  }

  for (int t = 0; t < NW; ++t){
    // prefetch NEXT step's gi (full step of latency cover)
    int tn = (t+1 < NW) ? (t+1) : t;
    const float* gt = gi + tn*NB*NG;
    float nr0 = gt[b0*NG+u0], nz0 = gt[b0*NG+NHID+u0], nn0 = gt[b0*NG+2*NHID+u0];
    float nr1 = 0.f, nz1 = 0.f, nn1 = 0.f;
    if (v1){ nr1 = gt[b1*NG+u1]; nz1 = gt[b1*NG+NHID+u1]; nn1 = gt[b1*NG+2*NHID+u1]; }

    if (wv < 8){
      bf8 A0 = HB[abase],    A1 = HB[abase+4],  A2 = HB[abase+8],
          A3 = HB[abase+12], A4 = HB[abase+16];
      f32x4 c0, c1, c2, c3;
      MMA_INIT(c0, A0, "a[0:3]",   "a0","a1","a2","a3")
      MMA_INIT(c1, A0, "a[20:23]", "a20","a21","a22","a23")
      MMA_INIT(c2, A0, "a[40:43]", "a40","a41","a42","a43")
      MMA_INIT(c3, A0, "a[60:63]", "a60","a61","a62","a63")
      MMA_ACC (c0, A1, "a[4:7]",   "a4","a5","a6","a7")
      MMA_ACC (c1, A1, "a[24:27]", "a24","a25","a26","a27")
      MMA_ACC (c2, A1, "a[44:47]", "a44","a45","a46","a47")
      MMA_ACC (c3, A1, "a[64:67]", "a64","a65","a66","a67")
      MMA_ACC (c0, A2, "a[8:11]",  "a8","a9","a10","a11")
      MMA_ACC (c1, A2, "a[28:31]", "a28","a29","a30","a31")
      MMA_ACC (c2, A2, "a[48:51]", "a48","a49","a50","a51")
      MMA_ACC (c3, A2, "a[68:71]", "a68","a69","a70","a71")
      MMA_ACC (c0, A3, "a[12:15]", "a12","a13","a14","a15")
      MMA_ACC (c1, A3, "a[32:35]", "a32","a33","a34","a35")
      MMA_ACC (c2, A3, "a[52:55]", "a52","a53","a54","a55")
      MMA_ACC (c3, A3, "a[72:75]", "a72","a73","a74","a75")
      MMA_ACC (c0, A4, "a[16:19]", "a16","a17","a18","a19")
      MMA_ACC (c1, A4, "a[36:39]", "a36","a37","a38","a39")
      MMA_ACC (c2, A4, "a[56:59]", "a56","a57","a58","a59")
      MMA_ACC (c3, A4, "a[76:79]", "a76","a77","a78","a79")
      asm volatile("s_nop 7\n\ts_nop 7" ::: );   // MFMA->VALU-read hazard cover

      // fold hi+lo (adjacent C rows, in-lane) and write folded gh
      int cb = agrp*2;
      float2 s0, s1, s2, s3;
      s0.x = c0[0]+c0[1]; s0.y = c0[2]+c0[3];
      s1.x = c1[0]+c1[1]; s1.y = c1[2]+c1[3];
      s2.x = c2[0]+c2[1]; s2.y = c2[2]+c2[3];
      s3.x = c3[0]+c3[1]; s3.y = c3[2]+c3[3];
      *(float2*)&gh[((wv    )*16 + arow)*10 + cb] = s0;
      *(float2*)&gh[((wv+ 8)*16 + arow)*10 + cb] = s1;
      *(float2*)&gh[((wv+16)*16 + arow)*10 + cb] = s2;
      *(float2*)&gh[((wv+24)*16 + arow)*10 + cb] = s3;
    }
    __syncthreads();

    // gate phase (hi+lo already folded): 3 LDS reads per triple
    {
      float r = sigmoidf_(cr0 + gh[u0*10 + b0]        + bhr0);
      float z = sigmoidf_(cz0 + gh[(NHID+u0)*10 + b0] + bhz0);
      float n = tanhf_  (cn0 + r*(gh[(2*NHID+u0)*10 + b0] + bhn0));
      float hn = (1.f - z)*n + z*hold0;
      hold0 = hn;
      unsigned int ub = __float_as_uint(hn);
      unsigned int hi = (ub + 0x7FFFu + ((ub>>16)&1u)) >> 16;
      h_bf[(2*b0)*184 + u0] = (unsigned short)hi;
      float lo = hn - __uint_as_float(hi<<16);
      unsigned int ul = __float_as_uint(lo);
      h_bf[(2*b0+1)*184 + u0] = (unsigned short)((ul + 0x7FFFu + ((ul>>16)&1u)) >> 16);
    }
    if (v1){
      float r = sigmoidf_(cr1 + gh[u1*10 + b1]        + bhr1);
      float z = sigmoidf_(cz1 + gh[(NHID+u1)*10 + b1] + bhz1);
      float n = tanhf_  (cn1 + r*(gh[(2*NHID+u1)*10 + b1] + bhn1));
      float hn = (1.f - z)*n + z*hold1;
      hold1 = hn;
      unsigned int ub = __float_as_uint(hn);
      unsigned int hi = (ub + 0x7FFFu + ((ub>>16)&1u)) >> 16;
      h_bf[(2*b1)*184 + u1] = (unsigned short)hi;
      float lo = hn - __uint_as_float(hi<<16);
      unsigned int ul = __float_as_uint(lo);
      h_bf[(2*b1+1)*184 + u1] = (unsigned short)((ul + 0x7FFFu + ((ul>>16)&1u)) >> 16);
    }
    __syncthreads();

    cr0 = nr0; cz0 = nz0; cn0 = nn0;
    cr1 = nr1; cz1 = nz1; cn1 = nn1;
  }

  out[b0*NHID + u0] = hold0;
  if (v1) out[b1*NHID + u1] = hold1;
}

extern "C" void kernel_launch(void* const* d_in, const int* in_sizes, int n_in,
                              void* d_out, int out_size, void* d_ws, size_t ws_size,
                              hipStream_t stream){
  const float* x       = (const float*)d_in[0];
  const float* conv_w  = (const float*)d_in[1];
  const float* conv_b  = (const float*)d_in[2];
  const float* f_lin_w = (const float*)d_in[3];
  const float* f_lin_b = (const float*)d_in[4];
  const float* f_a     = (const float*)d_in[5];
  const float* f_bias  = (const float*)d_in[6];
  const float* t_lin_w = (const float*)d_in[7];
  const float* t_lin_b = (const float*)d_in[8];
  const float* t_a     = (const float*)d_in[9];
  const float* t_bias  = (const float*)d_in[10];
  const float* w_ih    = (const float*)d_in[11];
  const float* w_hh    = (const float*)d_in[12];
  const float* b_ih    = (const float*)d_in[13];
  const float* b_hh    = (const float*)d_in[14];

  float* ws      = (float*)d_ws;
  float* xc      = ws;               // 160000
  float* conv_wT = ws + 160000;      // 70000
  float* si_f    = ws + 230000;      // 320000
  float* sj_f    = ws + 550000;      // 320000
  float* h_featT = ws + 870000;      // 160000
  float* si_t    = ws + 1030000;     // 320000
  float* sj_t    = ws + 1350000;     // 320000
  float* h_temp  = ws + 1670000;     // 160000
  float* w_ihT   = ws + 1830000;     // 135000
  float* gi      = ws + 1965000;     // 720000
  float* BfragF  = ws + 2685000;     // 40960 dwords (16B-aligned offset)
                                     // total 2725960 floats ~= 10.9 MB

  prep_kernel<<<961, 256, 0, stream>>>(conv_w, w_ih, w_hh, conv_wT, w_ihT, (unsigned int*)BfragF);
  conv_kernel<<<(NB*NW*NK + 255)/256, 256, 0, stream>>>(x, conv_b, conv_wT, xc);
  fgat_sisj<<<NB*25, 512, 0, stream>>>(xc, f_lin_w, si_f, sj_f);
  tgat_sisj<<<NB*50, 256, 0, stream>>>(xc, t_lin_w, si_t, sj_t);
  fgat_attn<<<NB*NK, 128, 0, stream>>>(xc, si_f, sj_f, f_lin_b, f_a, f_bias, h_featT);
  tgat_attn<<<NB*NW, 256, 0, stream>>>(xc, si_t, sj_t, t_lin_b, t_a, t_bias, h_temp);
  gi_kernel<<<NB*25, 512, 0, stream>>>(xc, h_featT, h_temp, w_ihT, b_ih, gi);
  gru_kernel<<<1, 768, 0, stream>>>(gi, (const int4*)BfragF, b_hh, (float*)d_out);
}

// Round 9
// 402.751 us; speedup vs baseline: 1.2420x; 1.0167x over previous
//
#include <hip/hip_runtime.h>
#include <math.h>

#define NB   8
#define NW   200
#define NK   100
#define KSZ  7
#define NHID 150
#define NFE  400
#define NTE  200
#define NG   450   // 3*HID
#define NCIN 300   // 3*K
#define ALPHAC 0.2f

typedef __attribute__((ext_vector_type(8))) short bf8;
typedef __attribute__((ext_vector_type(4))) float f32x4;

__device__ __forceinline__ float sigmoidf_(float x){
  return 1.0f/(1.0f + __expf(-x));
}
__device__ __forceinline__ float tanhf_(float x){
  float xc = fminf(fmaxf(x, -15.f), 15.f);
  float e = __expf(2.f*xc);
  return (e - 1.f)/(e + 1.f);
}
__device__ __forceinline__ unsigned short f2bf(float f){
  unsigned int u = __float_as_uint(f);
  unsigned int r = u + 0x7FFFu + ((u>>16)&1u);
  return (unsigned short)(r>>16);
}
__device__ __forceinline__ float lrelu_(float x){
  return fmaxf(x, 0.f) + ALPHAC*fminf(x, 0.f);
}

// ---------------- weight prep ----------------
__global__ void prep_kernel(const float* conv_w, const float* w_ih, const float* w_hh,
                            float* conv_wT, float* w_ihT, unsigned int* Bfrag){
  int idx = blockIdx.x*256 + threadIdx.x;
  const int n1 = NK*NK*KSZ;      // 70000
  const int n2 = NG*NCIN;        // 135000
  const int n3 = 32*5*64*4;      // 40960 dwords
  if (idx < n1){
    int k = idx % NK; int it = idx / NK;       // it = i*KSZ + t
    int i = it / KSZ, t = it % KSZ;
    conv_wT[idx] = conv_w[(k*NK + i)*KSZ + t];
  } else if (idx < n1 + n2){
    int o = idx - n1; int g = o % NG; int c = o / NG;
    w_ihT[o] = w_ih[g*NCIN + c];
  } else if (idx < n1 + n2 + n3){
    int o = idx - n1 - n2;
    int n   = o / 1280;
    int rem = o % 1280;
    int ks  = rem / 256;
    int rem2= rem % 256;
    int l   = rem2 >> 2;
    int d   = rem2 & 3;
    int col = n*16 + (l & 15);
    int k0  = ks*32 + (l >> 4)*8 + d*2;
    unsigned short lo = 0, hi = 0;
    if (col < NG){
      if (k0     < NHID) lo = f2bf(w_hh[col*NHID + k0]);
      if (k0 + 1 < NHID) hi = f2bf(w_hh[col*NHID + k0 + 1]);
    }
    Bfrag[o] = ((unsigned int)hi << 16) | lo;
  }
}

// ---------------- conv1d + bias + relu -> xc (B,W,K) ----------------
__global__ void conv_kernel(const float* x, const float* conv_b, const float* conv_wT, float* xc){
  int idx = blockIdx.x*256 + threadIdx.x;
  if (idx >= NB*NW*NK) return;
  int k = idx % NK; int w = (idx/NK) % NW; int b = idx/(NK*NW);
  float acc = conv_b[k];
  const float* xb = x + b*NW*NK;
  for (int t = 0; t < KSZ; ++t){
    int ws = w + t - 3;
    if (ws < 0 || ws >= NW) continue;
    const float* xr = xb + ws*NK;
    const float* wr = conv_wT + t*NK + k;   // (i*KSZ+t)*NK + k
    #pragma unroll 4
    for (int i = 0; i < NK; ++i){
      acc += xr[i] * wr[i*KSZ*NK];
    }
  }
  xc[idx] = fmaxf(acc, 0.0f);
}

// ---------------- f-GAT si/sj: (B,K,FE), nodes=features, v[b,n,d]=xc[b,d,n] ----------------
__global__ void fgat_sisj(const float* xc, const float* f_lin_w, float* si, float* sj){
  __shared__ __align__(16) float vt[NW*4];
  int b = blockIdx.x / 25; int n0 = (blockIdx.x % 25)*4;
  int tid = threadIdx.x;
  // float4 row-segment loads (n0 4-aligned, rows 400B-strided)
  for (int d = tid; d < NW; d += 512){
    float4 v = *(const float4*)&xc[(b*NW + d)*NK + n0];
    *(float4*)&vt[d*4] = v;
  }
  __syncthreads();
  if (tid >= NFE) return;
  int e = tid;
  float a1[4] = {0,0,0,0}, a2[4] = {0,0,0,0};
  for (int d = 0; d < NW; ++d){
    float w1 = f_lin_w[d*NFE + e];
    float w2 = f_lin_w[(NW + d)*NFE + e];
    float4 v = *(const float4*)&vt[d*4];
    a1[0] += v.x*w1; a1[1] += v.y*w1; a1[2] += v.z*w1; a1[3] += v.w*w1;
    a2[0] += v.x*w2; a2[1] += v.y*w2; a2[2] += v.z*w2; a2[3] += v.w*w2;
  }
  #pragma unroll
  for (int nn = 0; nn < 4; ++nn){
    si[(b*NK + n0+nn)*NFE + e] = a1[nn];
    sj[(b*NK + n0+nn)*NFE + e] = a2[nn];
  }
}

// ---------------- t-GAT si/sj: (B,W,TE), nodes=time, v[b,n,d]=xc[b,n,d] ----------------
__global__ void tgat_sisj(const float* xc, const float* t_lin_w, float* si, float* sj){
  __shared__ __align__(16) float vt[NK*4];
  int b = blockIdx.x / 50; int n0 = (blockIdx.x % 50)*4;
  int tid = threadIdx.x;
  // thread (nn, d4): float4 over d from row n0+nn (contiguous), scatter into vt
  for (int idx = tid; idx < 4*25; idx += 256){
    int nn = idx & 3; int d4 = idx >> 2;
    float4 v = *(const float4*)&xc[(b*NW + n0+nn)*NK + d4*4];
    vt[(d4*4+0)*4 + nn] = v.x;
    vt[(d4*4+1)*4 + nn] = v.y;
    vt[(d4*4+2)*4 + nn] = v.z;
    vt[(d4*4+3)*4 + nn] = v.w;
  }
  __syncthreads();
  if (tid >= NTE) return;
  int e = tid;
  float a1[4] = {0,0,0,0}, a2[4] = {0,0,0,0};
  for (int d = 0; d < NK; ++d){
    float w1 = t_lin_w[d*NTE + e];
    float w2 = t_lin_w[(NK + d)*NTE + e];
    float4 v = *(const float4*)&vt[d*4];
    a1[0] += v.x*w1; a1[1] += v.y*w1; a1[2] += v.z*w1; a1[3] += v.w*w1;
    a2[0] += v.x*w2; a2[1] += v.y*w2; a2[2] += v.z*w2; a2[3] += v.w*w2;
  }
  #pragma unroll
  for (int nn = 0; nn < 4; ++nn){
    si[(b*NW + n0+nn)*NTE + e] = a1[nn];
    sj[(b*NW + n0+nn)*NTE + e] = a2[nn];
  }
}

// ---------------- f-GAT attention fused ----------------
// out written transposed into (B,W,K): h_featT[b,d,i]
__global__ void fgat_attn(const float* xc, const float* si, const float* sj,
                          const float* f_lin_b, const float* f_a, const float* f_bias,
                          float* h_featT){
  __shared__ __align__(16) float sib[NFE];
  __shared__ __align__(16) float av[NFE];
  __shared__ __align__(16) float attn[NK];
  __shared__ float red[128];
  int b = blockIdx.x / NK, i = blockIdx.x % NK;
  int tid = threadIdx.x;
  {
    const float4* si4 = (const float4*)(si + (b*NK + i)*NFE);
    const float4* lb4 = (const float4*)f_lin_b;
    const float4* fa4 = (const float4*)f_a;
    for (int e4 = tid; e4 < NFE/4; e4 += 128){
      float4 s = si4[e4], l = lb4[e4];
      float4 o; o.x=s.x+l.x; o.y=s.y+l.y; o.z=s.z+l.z; o.w=s.w+l.w;
      *(float4*)&sib[e4*4] = o;
      *(float4*)&av[e4*4]  = fa4[e4];
    }
  }
  __syncthreads();
  float ej = -1e30f;
  if (tid < NK){
    const float4* sjr4 = (const float4*)(sj + (b*NK + tid)*NFE);
    const float4* sib4 = (const float4*)sib;
    const float4* av4  = (const float4*)av;
    float acc = 0.f;
    #pragma unroll 4
    for (int e4 = 0; e4 < NFE/4; ++e4){
      float4 s = sjr4[e4], t = sib4[e4], a = av4[e4];
      acc += a.x*lrelu_(t.x+s.x) + a.y*lrelu_(t.y+s.y)
           + a.z*lrelu_(t.z+s.z) + a.w*lrelu_(t.w+s.w);
    }
    ej = acc + f_bias[i*NK + tid];
  }
  red[tid] = ej; __syncthreads();
  for (int s = 64; s > 0; s >>= 1){ if (tid < s) red[tid] = fmaxf(red[tid], red[tid+s]); __syncthreads(); }
  float m = red[0]; __syncthreads();
  float ex = (tid < NK) ? __expf(ej - m) : 0.f;
  red[tid] = ex; __syncthreads();
  for (int s = 64; s > 0; s >>= 1){ if (tid < s) red[tid] += red[tid+s]; __syncthreads(); }
  float denom = red[0];
  if (tid < NK) attn[tid] = ex / denom;
  __syncthreads();
  for (int d = tid; d < NW; d += 128){
    const float4* xr4 = (const float4*)(xc + (b*NW + d)*NK);  // v[b,j,d] = xc[b,d,j]
    const float4* at4 = (const float4*)attn;
    float acc = 0.f;
    #pragma unroll 5
    for (int j4 = 0; j4 < NK/4; ++j4){
      float4 v = xr4[j4], a = at4[j4];
      acc += a.x*v.x + a.y*v.y + a.z*v.z + a.w*v.w;
    }
    h_featT[(b*NW + d)*NK + i] = sigmoidf_(acc);
  }
}

// ---------------- t-GAT attention fused -> h_temp (B,W,K) ----------------
__global__ void tgat_attn(const float* xc, const float* si, const float* sj,
                          const float* t_lin_b, const float* t_a, const float* t_bias,
                          float* h_temp){
  __shared__ __align__(16) float sib[NTE];
  __shared__ __align__(16) float av[NTE];
  __shared__ __align__(16) float attn[NW];
  __shared__ float red[256];
  int b = blockIdx.x / NW, i = blockIdx.x % NW;
  int tid = threadIdx.x;
  {
    const float4* si4 = (const float4*)(si + (b*NW + i)*NTE);
    const float4* lb4 = (const float4*)t_lin_b;
    const float4* ta4 = (const float4*)t_a;
    for (int e4 = tid; e4 < NTE/4; e4 += 256){
      float4 s = si4[e4], l = lb4[e4];
      float4 o; o.x=s.x+l.x; o.y=s.y+l.y; o.z=s.z+l.z; o.w=s.w+l.w;
      *(float4*)&sib[e4*4] = o;
      *(float4*)&av[e4*4]  = ta4[e4];
    }
  }
  __syncthreads();
  float ej = -1e30f;
  if (tid < NW){
    const float4* sjr4 = (const float4*)(sj + (b*NW + tid)*NTE);
    const float4* sib4 = (const float4*)sib;
    const float4* av4  = (const float4*)av;
    float acc = 0.f;
    #pragma unroll 4
    for (int e4 = 0; e4 < NTE/4; ++e4){
      float4 s = sjr4[e4], t = sib4[e4], a = av4[e4];
      acc += a.x*lrelu_(t.x+s.x) + a.y*lrelu_(t.y+s.y)
           + a.z*lrelu_(t.z+s.z) + a.w*lrelu_(t.w+s.w);
    }
    ej = acc + t_bias[i*NW + tid];
  }
  red[tid] = ej; __syncthreads();
  for (int s = 128; s > 0; s >>= 1){ if (tid < s) red[tid] = fmaxf(red[tid], red[tid+s]); __syncthreads(); }
  float m = red[0]; __syncthreads();
  float ex = (tid < NW) ? __expf(ej - m) : 0.f;
  red[tid] = ex; __syncthreads();
  for (int s = 128; s > 0; s >>= 1){ if (tid < s) red[tid] += red[tid+s]; __syncthreads(); }
  float denom = red[0];
  if (tid < NW) attn[tid] = ex / denom;
  __syncthreads();
  // lanes over d are coalesced (consecutive d); keep scalar j-loop
  for (int d = tid; d < NK; d += 256){
    float acc = 0.f;
    #pragma unroll 4
    for (int j = 0; j < NW; ++j) acc += attn[j]*xc[(b*NW + j)*NK + d];
    h_temp[(b*NW + i)*NK + d] = sigmoidf_(acc);
  }
}

// ---------------- gi = h_cat @ w_ih^T + b_ih, layout (t, b, g) ----------------
__global__ void gi_kernel(const float* xc, const float* h_featT, const float* h_temp,
                          const float* w_ihT, const float* b_ih, float* gi){
  __shared__ __align__(16) float hc[NCIN*8];   // [c][tt], stride 8
  int b = blockIdx.x / 25; int t0 = (blockIdx.x % 25)*8;
  int tid = threadIdx.x;
  for (int idx = tid; idx < NCIN*8; idx += 512){
    int tt = idx / NCIN; int c = idx % NCIN;
    int base = (b*NW + t0 + tt)*NK;
    float v;
    if (c < NK)        v = xc[base + c];
    else if (c < 2*NK) v = h_featT[base + c - NK];
    else               v = h_temp[base + c - 2*NK];
    hc[c*8 + tt] = v;
  }
  __syncthreads();
  if (tid >= NG) return;
  int g = tid;
  float bi = b_ih[g];
  float acc[8];
  #pragma unroll
  for (int tt = 0; tt < 8; ++tt) acc[tt] = bi;
  for (int c = 0; c < NCIN; ++c){
    float wv = w_ihT[c*NG + g];
    float4 h0 = *(const float4*)&hc[c*8];
    float4 h1 = *(const float4*)&hc[c*8+4];
    acc[0] += h0.x*wv; acc[1] += h0.y*wv; acc[2] += h0.z*wv; acc[3] += h0.w*wv;
    acc[4] += h1.x*wv; acc[5] += h1.y*wv; acc[6] += h1.z*wv; acc[7] += h1.w*wv;
  }
  #pragma unroll
  for (int tt = 0; tt < 8; ++tt)
    gi[((t0+tt)*NB + b)*NG + g] = acc[tt];
}

// ---------------- sequential GRU (unchanged from round 8) ----------------
#define STASH(B0,B1,B2,B3, FR) { \
  int4 wq = Bq[(FR)*64 + lane]; \
  asm volatile("v_accvgpr_write_b32 " B0 ", %0\n\t" \
               "v_accvgpr_write_b32 " B1 ", %1\n\t" \
               "v_accvgpr_write_b32 " B2 ", %2\n\t" \
               "v_accvgpr_write_b32 " B3 ", %3" \
               :: "v"(wq.x), "v"(wq.y), "v"(wq.z), "v"(wq.w) \
               : B0, B1, B2, B3); }
#define MMA_INIT(ACC, AF, BR, C0,C1,C2,C3) \
  asm volatile("v_mfma_f32_16x16x32_bf16 %0, %1, " BR ", 0" \
               : "=v"(ACC) : "v"(AF) : C0,C1,C2,C3);
#define MMA_ACC(ACC, AF, BR, C0,C1,C2,C3) \
  asm volatile("v_mfma_f32_16x16x32_bf16 %0, %1, " BR ", %0" \
               : "+v"(ACC) : "v"(AF) : C0,C1,C2,C3);

__global__ void __launch_bounds__(768) gru_kernel(const float* gi, const int4* Bq,
                                                  const float* b_hh, float* out){
  __shared__ __align__(16) unsigned short h_bf[16*184];  // row 2b=hi(b), 2b+1=lo(b); k-pad zeros
  __shared__ __align__(16) float gh[512*10];             // [col][8 batches + 2 pad], hi+lo folded
  int tid = threadIdx.x;
  int lane = tid & 63;
  int wv = tid >> 6;            // 0..11; waves 0..7 do MFMA (tiles wv, wv+8, wv+16, wv+24)
  int agrp = lane >> 4;         // 0..3
  int arow = lane & 15;

  int b0 = tid/NHID, u0 = tid%NHID;
  bool v1 = (tid < 432);
  int p1 = tid + 768;
  int b1 = v1 ? p1/NHID : 0, u1 = v1 ? p1%NHID : 0;
  float bhr0 = b_hh[u0], bhz0 = b_hh[NHID+u0], bhn0 = b_hh[2*NHID+u0];
  float bhr1 = b_hh[u1], bhz1 = b_hh[NHID+u1], bhn1 = b_hh[2*NHID+u1];

  if (wv < 8){
    STASH("a0","a1","a2","a3",     (wv)*5+0)
    STASH("a4","a5","a6","a7",     (wv)*5+1)
    STASH("a8","a9","a10","a11",   (wv)*5+2)
    STASH("a12","a13","a14","a15", (wv)*5+3)
    STASH("a16","a17","a18","a19", (wv)*5+4)
    STASH("a20","a21","a22","a23", (wv+8)*5+0)
    STASH("a24","a25","a26","a27", (wv+8)*5+1)
    STASH("a28","a29","a30","a31", (wv+8)*5+2)
    STASH("a32","a33","a34","a35", (wv+8)*5+3)
    STASH("a36","a37","a38","a39", (wv+8)*5+4)
    STASH("a40","a41","a42","a43", (wv+16)*5+0)
    STASH("a44","a45","a46","a47", (wv+16)*5+1)
    STASH("a48","a49","a50","a51", (wv+16)*5+2)
    STASH("a52","a53","a54","a55", (wv+16)*5+3)
    STASH("a56","a57","a58","a59", (wv+16)*5+4)
    STASH("a60","a61","a62","a63", (wv+24)*5+0)
    STASH("a64","a65","a66","a67", (wv+24)*5+1)
    STASH("a68","a69","a70","a71", (wv+24)*5+2)
    STASH("a72","a73","a74","a75", (wv+24)*5+3)
    STASH("a76","a77","a78","a79", (wv+24)*5+4)
  }

  for (int i = tid; i < 16*184; i += 768) h_bf[i] = 0;
  __syncthreads();

  const bf8* HB = (const bf8*)h_bf;
  int abase = arow*23 + agrp;   // bf8(16B) units; row stride 184 bf16 = 23 bf8

  float hold0 = 0.f, hold1 = 0.f;

  float cr0, cz0, cn0, cr1 = 0.f, cz1 = 0.f, cn1 = 0.f;
  {
    const float* g0 = gi + b0*NG;
    cr0 = g0[u0]; cz0 = g0[NHID+u0]; cn0 = g0[2*NHID+u0];
    if (v1){
      const float* g1 = gi + b1*NG;
      cr1 = g1[u1]; cz1 = g1[NHID+u1]; cn1 = g1[2*NHID+u1];
    }
  }

  for (int t = 0; t < NW; ++t){
    int tn = (t+1 < NW) ? (t+1) : t;
    const float* gt = gi + tn*NB*NG;
    float nr0 = gt[b0*NG+u0], nz0 = gt[b0*NG+NHID+u0], nn0 = gt[b0*NG+2*NHID+u0];
    float nr1 = 0.f, nz1 = 0.f, nn1 = 0.f;
    if (v1){ nr1 = gt[b1*NG+u1]; nz1 = gt[b1*NG+NHID+u1]; nn1 = gt[b1*NG+2*NHID+u1]; }

    if (wv < 8){
      bf8 A0 = HB[abase],    A1 = HB[abase+4],  A2 = HB[abase+8],
          A3 = HB[abase+12], A4 = HB[abase+16];
      f32x4 c0, c1, c2, c3;
      MMA_INIT(c0, A0, "a[0:3]",   "a0","a1","a2","a3")
      MMA_INIT(c1, A0, "a[20:23]", "a20","a21","a22","a23")
      MMA_INIT(c2, A0, "a[40:43]", "a40","a41","a42","a43")
      MMA_INIT(c3, A0, "a[60:63]", "a60","a61","a62","a63")
      MMA_ACC (c0, A1, "a[4:7]",   "a4","a5","a6","a7")
      MMA_ACC (c1, A1, "a[24:27]", "a24","a25","a26","a27")
      MMA_ACC (c2, A1, "a[44:47]", "a44","a45","a46","a47")
      MMA_ACC (c3, A1, "a[64:67]", "a64","a65","a66","a67")
      MMA_ACC (c0, A2, "a[8:11]",  "a8","a9","a10","a11")
      MMA_ACC (c1, A2, "a[28:31]", "a28","a29","a30","a31")
      MMA_ACC (c2, A2, "a[48:51]", "a48","a49","a50","a51")
      MMA_ACC (c3, A2, "a[68:71]", "a68","a69","a70","a71")
      MMA_ACC (c0, A3, "a[12:15]", "a12","a13","a14","a15")
      MMA_ACC (c1, A3, "a[32:35]", "a32","a33","a34","a35")
      MMA_ACC (c2, A3, "a[52:55]", "a52","a53","a54","a55")
      MMA_ACC (c3, A3, "a[72:75]", "a72","a73","a74","a75")
      MMA_ACC (c0, A4, "a[16:19]", "a16","a17","a18","a19")
      MMA_ACC (c1, A4, "a[36:39]", "a36","a37","a38","a39")
      MMA_ACC (c2, A4, "a[56:59]", "a56","a57","a58","a59")
      MMA_ACC (c3, A4, "a[76:79]", "a76","a77","a78","a79")
      asm volatile("s_nop 7\n\ts_nop 7" ::: );

      int cb = agrp*2;
      float2 s0, s1, s2, s3;
      s0.x = c0[0]+c0[1]; s0.y = c0[2]+c0[3];
      s1.x = c1[0]+c1[1]; s1.y = c1[2]+c1[3];
      s2.x = c2[0]+c2[1]; s2.y = c2[2]+c2[3];
      s3.x = c3[0]+c3[1]; s3.y = c3[2]+c3[3];
      *(float2*)&gh[((wv    )*16 + arow)*10 + cb] = s0;
      *(float2*)&gh[((wv+ 8)*16 + arow)*10 + cb] = s1;
      *(float2*)&gh[((wv+16)*16 + arow)*10 + cb] = s2;
      *(float2*)&gh[((wv+24)*16 + arow)*10 + cb] = s3;
    }
    __syncthreads();

    {
      float r = sigmoidf_(cr0 + gh[u0*10 + b0]        + bhr0);
      float z = sigmoidf_(cz0 + gh[(NHID+u0)*10 + b0] + bhz0);
      float n = tanhf_  (cn0 + r*(gh[(2*NHID+u0)*10 + b0] + bhn0));
      float hn = (1.f - z)*n + z*hold0;
      hold0 = hn;
      unsigned int ub = __float_as_uint(hn);
      unsigned int hi = (ub + 0x7FFFu + ((ub>>16)&1u)) >> 16;
      h_bf[(2*b0)*184 + u0] = (unsigned short)hi;
      float lo = hn - __uint_as_float(hi<<16);
      unsigned int ul = __float_as_uint(lo);
      h_bf[(2*b0+1)*184 + u0] = (unsigned short)((ul + 0x7FFFu + ((ul>>16)&1u)) >> 16);
    }
    if (v1){
      float r = sigmoidf_(cr1 + gh[u1*10 + b1]        + bhr1);
      float z = sigmoidf_(cz1 + gh[(NHID+u1)*10 + b1] + bhz1);
      float n = tanhf_  (cn1 + r*(gh[(2*NHID+u1)*10 + b1] + bhn1));
      float hn = (1.f - z)*n + z*hold1;
      hold1 = hn;
      unsigned int ub = __float_as_uint(hn);
      unsigned int hi = (ub + 0x7FFFu + ((ub>>16)&1u)) >> 16;
      h_bf[(2*b1)*184 + u1] = (unsigned short)hi;
      float lo = hn - __uint_as_float(hi<<16);
      unsigned int ul = __float_as_uint(lo);
      h_bf[(2*b1+1)*184 + u1] = (unsigned short)((ul + 0x7FFFu + ((ul>>16)&1u)) >> 16);
    }
    __syncthreads();

    cr0 = nr0; cz0 = nz0; cn0 = nn0;
    cr1 = nr1; cz1 = nz1; cn1 = nn1;
  }

  out[b0*NHID + u0] = hold0;
  if (v1) out[b1*NHID + u1] = hold1;
}

extern "C" void kernel_launch(void* const* d_in, const int* in_sizes, int n_in,
                              void* d_out, int out_size, void* d_ws, size_t ws_size,
                              hipStream_t stream){
  const float* x       = (const float*)d_in[0];
  const float* conv_w  = (const float*)d_in[1];
  const float* conv_b  = (const float*)d_in[2];
  const float* f_lin_w = (const float*)d_in[3];
  const float* f_lin_b = (const float*)d_in[4];
  const float* f_a     = (const float*)d_in[5];
  const float* f_bias  = (const float*)d_in[6];
  const float* t_lin_w = (const float*)d_in[7];
  const float* t_lin_b = (const float*)d_in[8];
  const float* t_a     = (const float*)d_in[9];
  const float* t_bias  = (const float*)d_in[10];
  const float* w_ih    = (const float*)d_in[11];
  const float* w_hh    = (const float*)d_in[12];
  const float* b_ih    = (const float*)d_in[13];
  const float* b_hh    = (const float*)d_in[14];

  float* ws      = (float*)d_ws;
  float* xc      = ws;               // 160000
  float* conv_wT = ws + 160000;      // 70000
  float* si_f    = ws + 230000;      // 320000
  float* sj_f    = ws + 550000;      // 320000
  float* h_featT = ws + 870000;      // 160000
  float* si_t    = ws + 1030000;     // 320000
  float* sj_t    = ws + 1350000;     // 320000
  float* h_temp  = ws + 1670000;     // 160000
  float* w_ihT   = ws + 1830000;     // 135000
  float* gi      = ws + 1965000;     // 720000
  float* BfragF  = ws + 2685000;     // 40960 dwords (16B-aligned offset)

  prep_kernel<<<961, 256, 0, stream>>>(conv_w, w_ih, w_hh, conv_wT, w_ihT, (unsigned int*)BfragF);
  conv_kernel<<<(NB*NW*NK + 255)/256, 256, 0, stream>>>(x, conv_b, conv_wT, xc);
  fgat_sisj<<<NB*25, 512, 0, stream>>>(xc, f_lin_w, si_f, sj_f);
  tgat_sisj<<<NB*50, 256, 0, stream>>>(xc, t_lin_w, si_t, sj_t);
  fgat_attn<<<NB*NK, 128, 0, stream>>>(xc, si_f, sj_f, f_lin_b, f_a, f_bias, h_featT);
  tgat_attn<<<NB*NW, 256, 0, stream>>>(xc, si_t, sj_t, t_lin_b, t_a, t_bias, h_temp);
  gi_kernel<<<NB*25, 512, 0, stream>>>(xc, h_featT, h_temp, w_ihT, b_ih, gi);
  gru_kernel<<<1, 768, 0, stream>>>(gi, (const int4*)BfragF, b_hh, (float*)d_out);
}

// Round 10
// 398.944 us; speedup vs baseline: 1.2538x; 1.0095x over previous
//
#include <hip/hip_runtime.h>
#include <math.h>

#define NB   8
#define NW   200
#define NK   100
#define KSZ  7
#define NHID 150
#define NFE  400
#define NTE  200
#define NG   450   // 3*HID
#define NCIN 300   // 3*K
#define ALPHAC 0.2f

typedef __attribute__((ext_vector_type(8))) short bf8;
typedef __attribute__((ext_vector_type(4))) float f32x4;

__device__ __forceinline__ float sigmoidf_(float x){
  return 1.0f/(1.0f + __expf(-x));
}
__device__ __forceinline__ float tanhf_(float x){
  float xc = fminf(fmaxf(x, -15.f), 15.f);
  float e = __expf(2.f*xc);
  return (e - 1.f)/(e + 1.f);
}
__device__ __forceinline__ unsigned short f2bf(float f){
  unsigned int u = __float_as_uint(f);
  unsigned int r = u + 0x7FFFu + ((u>>16)&1u);
  return (unsigned short)(r>>16);
}
__device__ __forceinline__ float lrelu_(float x){
  return fmaxf(x, 0.f) + ALPHAC*fminf(x, 0.f);
}

// ---------------- weight prep ----------------
__global__ void prep_kernel(const float* conv_w, const float* w_ih, const float* w_hh,
                            float* conv_wT, float* w_ihT, unsigned int* Bfrag){
  int idx = blockIdx.x*256 + threadIdx.x;
  const int n1 = NK*NK*KSZ;      // 70000
  const int n2 = NG*NCIN;        // 135000
  const int n3 = 32*5*64*4;      // 40960 dwords
  if (idx < n1){
    int k = idx % NK; int it = idx / NK;       // it = i*KSZ + t
    int i = it / KSZ, t = it % KSZ;
    conv_wT[idx] = conv_w[(k*NK + i)*KSZ + t];
  } else if (idx < n1 + n2){
    int o = idx - n1; int g = o % NG; int c = o / NG;
    w_ihT[o] = w_ih[g*NCIN + c];
  } else if (idx < n1 + n2 + n3){
    int o = idx - n1 - n2;
    int n   = o / 1280;
    int rem = o % 1280;
    int ks  = rem / 256;
    int rem2= rem % 256;
    int l   = rem2 >> 2;
    int d   = rem2 & 3;
    int col = n*16 + (l & 15);
    int k0  = ks*32 + (l >> 4)*8 + d*2;
    unsigned short lo = 0, hi = 0;
    if (col < NG){
      if (k0     < NHID) lo = f2bf(w_hh[col*NHID + k0]);
      if (k0 + 1 < NHID) hi = f2bf(w_hh[col*NHID + k0 + 1]);
    }
    Bfrag[o] = ((unsigned int)hi << 16) | lo;
  }
}

// ---------------- conv1d + bias + relu -> xc (B,W,K) ----------------
__global__ void conv_kernel(const float* x, const float* conv_b, const float* conv_wT, float* xc){
  int idx = blockIdx.x*256 + threadIdx.x;
  if (idx >= NB*NW*NK) return;
  int k = idx % NK; int w = (idx/NK) % NW; int b = idx/(NK*NW);
  float acc = conv_b[k];
  const float* xb = x + b*NW*NK;
  for (int t = 0; t < KSZ; ++t){
    int ws = w + t - 3;
    if (ws < 0 || ws >= NW) continue;
    const float* xr = xb + ws*NK;
    const float* wr = conv_wT + t*NK + k;   // (i*KSZ+t)*NK + k
    #pragma unroll 4
    for (int i = 0; i < NK; ++i){
      acc += xr[i] * wr[i*KSZ*NK];
    }
  }
  xc[idx] = fmaxf(acc, 0.0f);
}

// ---------------- fused si/sj kernel: blocks 0..199 f-GAT, 200..599 t-GAT ----------------
__global__ void sisj_fused(const float* xc, const float* f_lin_w, float* si_f, float* sj_f,
                           const float* t_lin_w, float* si_t, float* sj_t){
  __shared__ __align__(16) float vt[NW*4];
  int tid = threadIdx.x;
  if (blockIdx.x < 200){
    int b = blockIdx.x / 25; int n0 = (blockIdx.x % 25)*4;
    for (int d = tid; d < NW; d += 512){
      float4 v = *(const float4*)&xc[(b*NW + d)*NK + n0];
      *(float4*)&vt[d*4] = v;
    }
    __syncthreads();
    if (tid >= NFE) return;
    int e = tid;
    float a1[4] = {0,0,0,0}, a2[4] = {0,0,0,0};
    for (int d = 0; d < NW; ++d){
      float w1 = f_lin_w[d*NFE + e];
      float w2 = f_lin_w[(NW + d)*NFE + e];
      float4 v = *(const float4*)&vt[d*4];
      a1[0] += v.x*w1; a1[1] += v.y*w1; a1[2] += v.z*w1; a1[3] += v.w*w1;
      a2[0] += v.x*w2; a2[1] += v.y*w2; a2[2] += v.z*w2; a2[3] += v.w*w2;
    }
    #pragma unroll
    for (int nn = 0; nn < 4; ++nn){
      si_f[(b*NK + n0+nn)*NFE + e] = a1[nn];
      sj_f[(b*NK + n0+nn)*NFE + e] = a2[nn];
    }
  } else {
    int bi = blockIdx.x - 200;
    int b = bi / 50; int n0 = (bi % 50)*4;
    for (int idx = tid; idx < 4*25; idx += 512){
      int nn = idx & 3; int d4 = idx >> 2;
      float4 v = *(const float4*)&xc[(b*NW + n0+nn)*NK + d4*4];
      vt[(d4*4+0)*4 + nn] = v.x;
      vt[(d4*4+1)*4 + nn] = v.y;
      vt[(d4*4+2)*4 + nn] = v.z;
      vt[(d4*4+3)*4 + nn] = v.w;
    }
    __syncthreads();
    if (tid >= NTE) return;
    int e = tid;
    float a1[4] = {0,0,0,0}, a2[4] = {0,0,0,0};
    for (int d = 0; d < NK; ++d){
      float w1 = t_lin_w[d*NTE + e];
      float w2 = t_lin_w[(NK + d)*NTE + e];
      float4 v = *(const float4*)&vt[d*4];
      a1[0] += v.x*w1; a1[1] += v.y*w1; a1[2] += v.z*w1; a1[3] += v.w*w1;
      a2[0] += v.x*w2; a2[1] += v.y*w2; a2[2] += v.z*w2; a2[3] += v.w*w2;
    }
    #pragma unroll
    for (int nn = 0; nn < 4; ++nn){
      si_t[(b*NW + n0+nn)*NTE + e] = a1[nn];
      sj_t[(b*NW + n0+nn)*NTE + e] = a2[nn];
    }
  }
}

// ---------------- fused attention: blocks 0..799 f-GAT, 800..2399 t-GAT ----------------
// 256 threads / 4 waves; softmax reductions via wave shfl_xor (3 barriers, was ~16)
__global__ void attn_fused(const float* xc,
                           const float* si_f, const float* sj_f, const float* f_lin_b,
                           const float* f_a, const float* f_bias,
                           const float* si_t, const float* sj_t, const float* t_lin_b,
                           const float* t_a, const float* t_bias,
                           float* h_featT, float* h_temp){
  __shared__ __align__(16) float sib[NFE];
  __shared__ __align__(16) float av[NFE];
  __shared__ __align__(16) float attn[NW];
  __shared__ float red[8];
  int tid = threadIdx.x, lane = tid & 63, wid = tid >> 6;
  if (blockIdx.x < NB*NK){
    int b = blockIdx.x / NK, i = blockIdx.x % NK;
    {
      const float4* si4 = (const float4*)(si_f + (b*NK + i)*NFE);
      const float4* lb4 = (const float4*)f_lin_b;
      const float4* fa4 = (const float4*)f_a;
      for (int e4 = tid; e4 < NFE/4; e4 += 256){
        float4 s = si4[e4], l = lb4[e4];
        float4 o; o.x=s.x+l.x; o.y=s.y+l.y; o.z=s.z+l.z; o.w=s.w+l.w;
        *(float4*)&sib[e4*4] = o;
        *(float4*)&av[e4*4]  = fa4[e4];
      }
    }
    __syncthreads();
    float ej = -1e30f;
    if (tid < NK){
      const float4* sjr4 = (const float4*)(sj_f + (b*NK + tid)*NFE);
      const float4* sib4 = (const float4*)sib;
      const float4* av4  = (const float4*)av;
      float acc = 0.f;
      #pragma unroll 4
      for (int e4 = 0; e4 < NFE/4; ++e4){
        float4 s = sjr4[e4], t = sib4[e4], a = av4[e4];
        acc += a.x*lrelu_(t.x+s.x) + a.y*lrelu_(t.y+s.y)
             + a.z*lrelu_(t.z+s.z) + a.w*lrelu_(t.w+s.w);
      }
      ej = acc + f_bias[i*NK + tid];
    }
    float m = ej;
    #pragma unroll
    for (int off = 32; off > 0; off >>= 1) m = fmaxf(m, __shfl_xor(m, off));
    if (lane == 0) red[wid] = m;
    __syncthreads();
    float bm = fmaxf(fmaxf(red[0], red[1]), fmaxf(red[2], red[3]));
    float ex = (tid < NK) ? __expf(ej - bm) : 0.f;
    float s = ex;
    #pragma unroll
    for (int off = 32; off > 0; off >>= 1) s += __shfl_xor(s, off);
    if (lane == 0) red[4 + wid] = s;
    __syncthreads();
    float denom = red[4] + red[5] + red[6] + red[7];
    if (tid < NK) attn[tid] = ex / denom;
    __syncthreads();
    for (int d = tid; d < NW; d += 256){
      const float4* xr4 = (const float4*)(xc + (b*NW + d)*NK);  // v[b,j,d] = xc[b,d,j]
      const float4* at4 = (const float4*)attn;
      float acc = 0.f;
      #pragma unroll 5
      for (int j4 = 0; j4 < NK/4; ++j4){
        float4 v = xr4[j4], a = at4[j4];
        acc += a.x*v.x + a.y*v.y + a.z*v.z + a.w*v.w;
      }
      h_featT[(b*NW + d)*NK + i] = sigmoidf_(acc);
    }
  } else {
    int bi = blockIdx.x - NB*NK;
    int b = bi / NW, i = bi % NW;
    {
      const float4* si4 = (const float4*)(si_t + (b*NW + i)*NTE);
      const float4* lb4 = (const float4*)t_lin_b;
      const float4* ta4 = (const float4*)t_a;
      for (int e4 = tid; e4 < NTE/4; e4 += 256){
        float4 s = si4[e4], l = lb4[e4];
        float4 o; o.x=s.x+l.x; o.y=s.y+l.y; o.z=s.z+l.z; o.w=s.w+l.w;
        *(float4*)&sib[e4*4] = o;
        *(float4*)&av[e4*4]  = ta4[e4];
      }
    }
    __syncthreads();
    float ej = -1e30f;
    if (tid < NW){
      const float4* sjr4 = (const float4*)(sj_t + (b*NW + tid)*NTE);
      const float4* sib4 = (const float4*)sib;
      const float4* av4  = (const float4*)av;
      float acc = 0.f;
      #pragma unroll 4
      for (int e4 = 0; e4 < NTE/4; ++e4){
        float4 s = sjr4[e4], t = sib4[e4], a = av4[e4];
        acc += a.x*lrelu_(t.x+s.x) + a.y*lrelu_(t.y+s.y)
             + a.z*lrelu_(t.z+s.z) + a.w*lrelu_(t.w+s.w);
      }
      ej = acc + t_bias[i*NW + tid];
    }
    float m = ej;
    #pragma unroll
    for (int off = 32; off > 0; off >>= 1) m = fmaxf(m, __shfl_xor(m, off));
    if (lane == 0) red[wid] = m;
    __syncthreads();
    float bm = fmaxf(fmaxf(red[0], red[1]), fmaxf(red[2], red[3]));
    float ex = (tid < NW) ? __expf(ej - bm) : 0.f;
    float s = ex;
    #pragma unroll
    for (int off = 32; off > 0; off >>= 1) s += __shfl_xor(s, off);
    if (lane == 0) red[4 + wid] = s;
    __syncthreads();
    float denom = red[4] + red[5] + red[6] + red[7];
    if (tid < NW) attn[tid] = ex / denom;
    __syncthreads();
    for (int d = tid; d < NK; d += 256){
      float acc = 0.f;
      #pragma unroll 4
      for (int j = 0; j < NW; ++j) acc += attn[j]*xc[(b*NW + j)*NK + d];
      h_temp[(b*NW + i)*NK + d] = sigmoidf_(acc);
    }
  }
}

// ---------------- gi = h_cat @ w_ih^T + b_ih (+ b_hh r/z folded), layout (t, b, g) ----------------
__global__ void gi_kernel(const float* xc, const float* h_featT, const float* h_temp,
                          const float* w_ihT, const float* b_ih, const float* b_hh, float* gi){
  __shared__ __align__(16) float hc[NCIN*8];   // [c][tt], stride 8
  int b = blockIdx.x / 25; int t0 = (blockIdx.x % 25)*8;
  int tid = threadIdx.x;
  for (int idx = tid; idx < NCIN*8; idx += 512){
    int tt = idx / NCIN; int c = idx % NCIN;
    int base = (b*NW + t0 + tt)*NK;
    float v;
    if (c < NK)        v = xc[base + c];
    else if (c < 2*NK) v = h_featT[base + c - NK];
    else               v = h_temp[base + c - 2*NK];
    hc[c*8 + tt] = v;
  }
  __syncthreads();
  if (tid >= NG) return;
  int g = tid;
  // fold b_hh for r,z gates (g < 2*NHID); n-gate bias stays in GRU (scaled by r)
  float bi = b_ih[g] + ((g < 2*NHID) ? b_hh[g] : 0.f);
  float acc[8];
  #pragma unroll
  for (int tt = 0; tt < 8; ++tt) acc[tt] = bi;
  for (int c = 0; c < NCIN; ++c){
    float wv = w_ihT[c*NG + g];
    float4 h0 = *(const float4*)&hc[c*8];
    float4 h1 = *(const float4*)&hc[c*8+4];
    acc[0] += h0.x*wv; acc[1] += h0.y*wv; acc[2] += h0.z*wv; acc[3] += h0.w*wv;
    acc[4] += h1.x*wv; acc[5] += h1.y*wv; acc[6] += h1.z*wv; acc[7] += h1.w*wv;
  }
  #pragma unroll
  for (int tt = 0; tt < 8; ++tt)
    gi[((t0+tt)*NB + b)*NG + g] = acc[tt];
}

// ---------------- sequential GRU (round-8 structure + VALU trims) ----------------
#define STASH(B0,B1,B2,B3, FR) { \
  int4 wq = Bq[(FR)*64 + lane]; \
  asm volatile("v_accvgpr_write_b32 " B0 ", %0\n\t" \
               "v_accvgpr_write_b32 " B1 ", %1\n\t" \
               "v_accvgpr_write_b32 " B2 ", %2\n\t" \
               "v_accvgpr_write_b32 " B3 ", %3" \
               :: "v"(wq.x), "v"(wq.y), "v"(wq.z), "v"(wq.w) \
               : B0, B1, B2, B3); }
#define MMA_INIT(ACC, AF, BR, C0,C1,C2,C3) \
  asm volatile("v_mfma_f32_16x16x32_bf16 %0, %1, " BR ", 0" \
               : "=v"(ACC) : "v"(AF) : C0,C1,C2,C3);
#define MMA_ACC(ACC, AF, BR, C0,C1,C2,C3) \
  asm volatile("v_mfma_f32_16x16x32_bf16 %0, %1, " BR ", %0" \
               : "+v"(ACC) : "v"(AF) : C0,C1,C2,C3);

// pack f32 -> (hi bf16, lo bf16) with v_cvt_pk (1 instr per convert vs ~5 manual)
__device__ __forceinline__ void pack_hilo(float hn, unsigned int& hi2, unsigned int& lo2){
  asm("v_cvt_pk_bf16_f32 %0, %1, %1" : "=v"(hi2) : "v"(hn));
  float hif = __uint_as_float(hi2 << 16);
  float lo = hn - hif;
  asm("v_cvt_pk_bf16_f32 %0, %1, %1" : "=v"(lo2) : "v"(lo));
}

__global__ void __launch_bounds__(768) gru_kernel(const float* gi, const int4* Bq,
                                                  const float* b_hh, float* out){
  __shared__ __align__(16) unsigned short h_bf[16*184];  // row 2b=hi(b), 2b+1=lo(b)
  __shared__ __align__(16) float gh[512*10];             // [col][8 batches + 2 pad], hi+lo folded
  int tid = threadIdx.x;
  int lane = tid & 63;
  int wv = tid >> 6;            // 0..11; waves 0..7 do MFMA
  int agrp = lane >> 4;
  int arow = lane & 15;

  int b0 = tid/NHID, u0 = tid%NHID;
  bool v1 = (tid < 432);
  int p1 = tid + 768;
  int b1 = v1 ? p1/NHID : 0, u1 = v1 ? p1%NHID : 0;
  float bhn0 = b_hh[2*NHID+u0];
  float bhn1 = b_hh[2*NHID+u1];

  if (wv < 8){
    STASH("a0","a1","a2","a3",     (wv)*5+0)
    STASH("a4","a5","a6","a7",     (wv)*5+1)
    STASH("a8","a9","a10","a11",   (wv)*5+2)
    STASH("a12","a13","a14","a15", (wv)*5+3)
    STASH("a16","a17","a18","a19", (wv)*5+4)
    STASH("a20","a21","a22","a23", (wv+8)*5+0)
    STASH("a24","a25","a26","a27", (wv+8)*5+1)
    STASH("a28","a29","a30","a31", (wv+8)*5+2)
    STASH("a32","a33","a34","a35", (wv+8)*5+3)
    STASH("a36","a37","a38","a39", (wv+8)*5+4)
    STASH("a40","a41","a42","a43", (wv+16)*5+0)
    STASH("a44","a45","a46","a47", (wv+16)*5+1)
    STASH("a48","a49","a50","a51", (wv+16)*5+2)
    STASH("a52","a53","a54","a55", (wv+16)*5+3)
    STASH("a56","a57","a58","a59", (wv+16)*5+4)
    STASH("a60","a61","a62","a63", (wv+24)*5+0)
    STASH("a64","a65","a66","a67", (wv+24)*5+1)
    STASH("a68","a69","a70","a71", (wv+24)*5+2)
    STASH("a72","a73","a74","a75", (wv+24)*5+3)
    STASH("a76","a77","a78","a79", (wv+24)*5+4)
  }

  for (int i = tid; i < 16*184; i += 768) h_bf[i] = 0;
  __syncthreads();

  const bf8* HB = (const bf8*)h_bf;
  int abase = arow*23 + agrp;

  float hold0 = 0.f, hold1 = 0.f;

  // pointer-increment gi prefetch (immediate offsets 0 / 600B / 1200B)
  const float* gp0 = gi + b0*NG + u0;
  const float* gp1 = gi + b1*NG + u1;
  float cr0 = gp0[0], cz0 = gp0[NHID], cn0 = gp0[2*NHID];
  float cr1 = 0.f, cz1 = 0.f, cn1 = 0.f;
  if (v1){ cr1 = gp1[0]; cz1 = gp1[NHID]; cn1 = gp1[2*NHID]; }

  // LDS gate-read bases are loop-invariant
  const float* ghp0 = &gh[u0*10 + b0];
  const float* ghp1 = &gh[u1*10 + b1];
  unsigned short* hb0h = &h_bf[(2*b0)*184 + u0];
  unsigned short* hb0l = &h_bf[(2*b0+1)*184 + u0];
  unsigned short* hb1h = &h_bf[(2*b1)*184 + u1];
  unsigned short* hb1l = &h_bf[(2*b1+1)*184 + u1];

  for (int t = 0; t < NW; ++t){
    // prefetch next step (last iteration reads past gi into Bfrag region: unused)
    gp0 += NB*NG; gp1 += NB*NG;
    float nr0 = gp0[0], nz0 = gp0[NHID], nn0 = gp0[2*NHID];
    float nr1 = 0.f, nz1 = 0.f, nn1 = 0.f;
    if (v1){ nr1 = gp1[0]; nz1 = gp1[NHID]; nn1 = gp1[2*NHID]; }

    if (wv < 8){
      bf8 A0 = HB[abase],    A1 = HB[abase+4],  A2 = HB[abase+8],
          A3 = HB[abase+12], A4 = HB[abase+16];
      f32x4 c0, c1, c2, c3;
      MMA_INIT(c0, A0, "a[0:3]",   "a0","a1","a2","a3")
      MMA_INIT(c1, A0, "a[20:23]", "a20","a21","a22","a23")
      MMA_INIT(c2, A0, "a[40:43]", "a40","a41","a42","a43")
      MMA_INIT(c3, A0, "a[60:63]", "a60","a61","a62","a63")
      MMA_ACC (c0, A1, "a[4:7]",   "a4","a5","a6","a7")
      MMA_ACC (c1, A1, "a[24:27]", "a24","a25","a26","a27")
      MMA_ACC (c2, A1, "a[44:47]", "a44","a45","a46","a47")
      MMA_ACC (c3, A1, "a[64:67]", "a64","a65","a66","a67")
      MMA_ACC (c0, A2, "a[8:11]",  "a8","a9","a10","a11")
      MMA_ACC (c1, A2, "a[28:31]", "a28","a29","a30","a31")
      MMA_ACC (c2, A2, "a[48:51]", "a48","a49","a50","a51")
      MMA_ACC (c3, A2, "a[68:71]", "a68","a69","a70","a71")
      MMA_ACC (c0, A3, "a[12:15]", "a12","a13","a14","a15")
      MMA_ACC (c1, A3, "a[32:35]", "a32","a33","a34","a35")
      MMA_ACC (c2, A3, "a[52:55]", "a52","a53","a54","a55")
      MMA_ACC (c3, A3, "a[72:75]", "a72","a73","a74","a75")
      MMA_ACC (c0, A4, "a[16:19]", "a16","a17","a18","a19")
      MMA_ACC (c1, A4, "a[36:39]", "a36","a37","a38","a39")
      MMA_ACC (c2, A4, "a[56:59]", "a56","a57","a58","a59")
      MMA_ACC (c3, A4, "a[76:79]", "a76","a77","a78","a79")
      asm volatile("s_nop 7\n\ts_nop 7" ::: );

      int cb = agrp*2;
      float2 s0, s1, s2, s3;
      s0.x = c0[0]+c0[1]; s0.y = c0[2]+c0[3];
      s1.x = c1[0]+c1[1]; s1.y = c1[2]+c1[3];
      s2.x = c2[0]+c2[1]; s2.y = c2[2]+c2[3];
      s3.x = c3[0]+c3[1]; s3.y = c3[2]+c3[3];
      *(float2*)&gh[((wv    )*16 + arow)*10 + cb] = s0;
      *(float2*)&gh[((wv+ 8)*16 + arow)*10 + cb] = s1;
      *(float2*)&gh[((wv+16)*16 + arow)*10 + cb] = s2;
      *(float2*)&gh[((wv+24)*16 + arow)*10 + cb] = s3;
    }
    __syncthreads();

    {
      float r = sigmoidf_(cr0 + ghp0[0]);           // b_hh_r folded into gi
      float z = sigmoidf_(cz0 + ghp0[NHID*10]);     // b_hh_z folded into gi
      float n = tanhf_  (cn0 + r*(ghp0[2*NHID*10] + bhn0));
      float hn = (1.f - z)*n + z*hold0;
      hold0 = hn;
      unsigned int hi2, lo2;
      pack_hilo(hn, hi2, lo2);
      *hb0h = (unsigned short)hi2;
      *hb0l = (unsigned short)lo2;
    }
    if (v1){
      float r = sigmoidf_(cr1 + ghp1[0]);
      float z = sigmoidf_(cz1 + ghp1[NHID*10]);
      float n = tanhf_  (cn1 + r*(ghp1[2*NHID*10] + bhn1));
      float hn = (1.f - z)*n + z*hold1;
      hold1 = hn;
      unsigned int hi2, lo2;
      pack_hilo(hn, hi2, lo2);
      *hb1h = (unsigned short)hi2;
      *hb1l = (unsigned short)lo2;
    }
    __syncthreads();

    cr0 = nr0; cz0 = nz0; cn0 = nn0;
    cr1 = nr1; cz1 = nz1; cn1 = nn1;
  }

  out[b0*NHID + u0] = hold0;
  if (v1) out[b1*NHID + u1] = hold1;
}

extern "C" void kernel_launch(void* const* d_in, const int* in_sizes, int n_in,
                              void* d_out, int out_size, void* d_ws, size_t ws_size,
                              hipStream_t stream){
  const float* x       = (const float*)d_in[0];
  const float* conv_w  = (const float*)d_in[1];
  const float* conv_b  = (const float*)d_in[2];
  const float* f_lin_w = (const float*)d_in[3];
  const float* f_lin_b = (const float*)d_in[4];
  const float* f_a     = (const float*)d_in[5];
  const float* f_bias  = (const float*)d_in[6];
  const float* t_lin_w = (const float*)d_in[7];
  const float* t_lin_b = (const float*)d_in[8];
  const float* t_a     = (const float*)d_in[9];
  const float* t_bias  = (const float*)d_in[10];
  const float* w_ih    = (const float*)d_in[11];
  const float* w_hh    = (const float*)d_in[12];
  const float* b_ih    = (const float*)d_in[13];
  const float* b_hh    = (const float*)d_in[14];

  float* ws      = (float*)d_ws;
  float* xc      = ws;               // 160000
  float* conv_wT = ws + 160000;      // 70000
  float* si_f    = ws + 230000;      // 320000
  float* sj_f    = ws + 550000;      // 320000
  float* h_featT = ws + 870000;      // 160000
  float* si_t    = ws + 1030000;     // 320000
  float* sj_t    = ws + 1350000;     // 320000
  float* h_temp  = ws + 1670000;     // 160000
  float* w_ihT   = ws + 1830000;     // 135000
  float* gi      = ws + 1965000;     // 720000
  float* BfragF  = ws + 2685000;     // 40960 dwords

  prep_kernel<<<961, 256, 0, stream>>>(conv_w, w_ih, w_hh, conv_wT, w_ihT, (unsigned int*)BfragF);
  conv_kernel<<<(NB*NW*NK + 255)/256, 256, 0, stream>>>(x, conv_b, conv_wT, xc);
  sisj_fused<<<600, 512, 0, stream>>>(xc, f_lin_w, si_f, sj_f, t_lin_w, si_t, sj_t);
  attn_fused<<<2400, 256, 0, stream>>>(xc, si_f, sj_f, f_lin_b, f_a, f_bias,
                                       si_t, sj_t, t_lin_b, t_a, t_bias, h_featT, h_temp);
  gi_kernel<<<200, 512, 0, stream>>>(xc, h_featT, h_temp, w_ihT, b_ih, b_hh, gi);
  gru_kernel<<<1, 768, 0, stream>>>(gi, (const int4*)BfragF, b_hh, (float*)d_out);
}